// Round 12
// baseline (279.159 us; speedup 1.0000x reference)
//
#include <hip/hip_runtime.h>

// LCT FK-migration: 3D FFT(512,256,256) -> Stolt trilinear resample -> 3D IFFT -> |.|^2
// Single 256 MiB workspace buffer V = [512][256][256] cpx, flat (z<<16)+(y<<8)+x.
// x/y spectra stored FFTSHIFTED with the half-pixel Stolt x/y blurs folded into the
// forward x/y FFT stores (ix = xs-0.5, iy = ys-0.5 exactly => fx=fy=0.5 fixed blur).
// Z-stage SPLIT (fusion lost — rounds 7/8): k_fft_z_fwd writes shifted z-spectrum to
// planes 256..511; k_stolt_fftz_inv stages its partner source column into LDS rows
// 256..511 (coalesced), does the z-only gather FROM LDS into rows 0..255 (iz0>=256
// always; disjoint), then the inverse z-FFT in place, writing planes 0..255.
// Inverse y (crop y<128) and inverse x + |.|^2 (crop x<128) finish.
// Complex algebra as ext_vector<2 x float> for packed v_pk_*_f32 (VOP3P).
// Twiddles stored as float4 (c, c, -s, s): cmul(a,w) = a*wl + swap(a)*wh.

typedef float __attribute__((ext_vector_type(2))) cpx;

__device__ float4 g_tw4[512];   // (c, c, -s, s), (c,s) = exp(-2*pi*i*k/512)

__device__ __forceinline__ cpx cswap(cpx a){ return __builtin_shufflevector(a, a, 1, 0); }
// -i*a = (a.y, -a.x)
__device__ __forceinline__ cpx cmji(cpx a){ return cswap(a)*(cpx){1.0f, -1.0f}; }
// +i*a = (-a.y, a.x)
__device__ __forceinline__ cpx cmpi(cpx a){ return cswap(a)*(cpx){-1.0f, 1.0f}; }

// base-4 digit reversal of an 8-bit index
__device__ __forceinline__ int rev4_8(int k){
    return ((k & 3) << 6) | ((k & 12) << 2) | ((k >> 2) & 12) | (k >> 6);
}

// ---------------- twiddle table (double-computed for accuracy) ----------------
__global__ void k_tw(){
    int j = threadIdx.x;                        // 512 threads
    double a = -2.0*3.14159265358979323846*(double)j/512.0;
    float c = (float)cos(a), s = (float)sin(a);
    g_tw4[j] = make_float4(c, c, -s, s);
}

template<bool INV>
__device__ __forceinline__ cpx twmul(cpx a, int k){
    float4 t = g_tw4[k & 511];
    cpx wl = {t.x, t.y};                        // (c, c)
    cpx wh = {t.z, t.w};                        // (-s, s)
    cpx r = a*wl;
    return INV ? (r - cswap(a)*wh) : (r + cswap(a)*wh);
}

// ---------------- radix-4 DIF butterfly (packed, in-register), full ----------------
template<bool INV>
__device__ __forceinline__ void dft4(cpx* x){
    cpx e0 = x[0] + x[2], e1 = x[0] - x[2];
    cpx o0 = x[1] + x[3], o1 = x[1] - x[3];
    x[0] = e0 + o0;
    x[2] = e0 - o0;
    cpx j1 = INV ? cmpi(o1) : cmji(o1);
    x[1] = e1 + j1;
    x[3] = e1 - j1;
}

// radix-4 with x[2]=x[3]=0 (half-support input): inputs in x[0],x[1]
template<bool INV>
__device__ __forceinline__ void dft4_h2(cpx* x){
    cpx a0 = x[0], a1 = x[1];
    x[0] = a0 + a1;
    x[2] = a0 - a1;
    cpx j1 = INV ? cmpi(a1) : cmji(a1);
    x[1] = a0 + j1;
    x[3] = a0 - j1;
}

// radix-4 computing only outputs 0,1 (the '+' half)
template<bool INV>
__device__ __forceinline__ void dft4_lo2(cpx* x){
    cpx e0 = x[0] + x[2], e1 = x[0] - x[2];
    cpx o0 = x[1] + x[3], o1 = x[1] - x[3];
    x[0] = e0 + o0;
    x[1] = e1 + (INV ? cmpi(o1) : cmji(o1));
}

// ---------------- radix-8 DIF butterfly (packed, in-register), full ----------------
template<bool INV>
__device__ __forceinline__ void dft8(cpx* x){
    const float s = 0.70710678118654752440f;
    cpx e0 = x[0] + x[4], e2 = x[0] - x[4];
    cpx e1 = x[2] + x[6], e3 = x[2] - x[6];
    cpx E0 = e0 + e1, E2 = e0 - e1;
    cpx j3 = INV ? cmpi(e3) : cmji(e3);
    cpx E1 = e2 + j3, E3 = e2 - j3;
    cpx o0 = x[1] + x[5], o2 = x[1] - x[5];
    cpx o1 = x[3] + x[7], o3 = x[3] - x[7];
    cpx O0 = o0 + o1, O2 = o0 - o1;
    cpx k3 = INV ? cmpi(o3) : cmji(o3);
    cpx O1 = o2 + k3, O3 = o2 - k3;
    cpx W1, W2, W3;
    if (!INV){
        W1 = s*(O1 + cmji(O1));
        W2 = cmji(O2);
        W3 = s*(cmji(O3) - O3);
    } else {
        W1 = s*(O1 + cmpi(O1));
        W2 = cmpi(O2);
        W3 = s*(cmpi(O3) - O3);
    }
    x[0] = E0 + O0; x[4] = E0 - O0;
    x[1] = E1 + W1; x[5] = E1 - W1;
    x[2] = E2 + W2; x[6] = E2 - W2;
    x[3] = E3 + W3; x[7] = E3 - W3;
}

// radix-8 with x[4..7]=0: inputs in x[0..3], writes all 8 outputs
template<bool INV>
__device__ __forceinline__ void dft8_h4(cpx* x){
    const float s = 0.70710678118654752440f;
    cpx a0 = x[0], a1 = x[1], a2 = x[2], a3 = x[3];
    cpx E0 = a0 + a2, E2 = a0 - a2;
    cpx j3 = INV ? cmpi(a2) : cmji(a2);
    cpx E1 = a0 + j3, E3 = a0 - j3;
    cpx O0 = a1 + a3, O2 = a1 - a3;
    cpx k3 = INV ? cmpi(a3) : cmji(a3);
    cpx O1 = a1 + k3, O3 = a1 - k3;
    cpx W1, W2, W3;
    if (!INV){
        W1 = s*(O1 + cmji(O1));
        W2 = cmji(O2);
        W3 = s*(cmji(O3) - O3);
    } else {
        W1 = s*(O1 + cmpi(O1));
        W2 = cmpi(O2);
        W3 = s*(cmpi(O3) - O3);
    }
    x[0] = E0 + O0; x[4] = E0 - O0;
    x[1] = E1 + W1; x[5] = E1 - W1;
    x[2] = E2 + W2; x[6] = E2 - W2;
    x[3] = E3 + W3; x[7] = E3 - W3;
}

// radix-8 computing only outputs 0..3 (the '+' half)
template<bool INV>
__device__ __forceinline__ void dft8_lo4(cpx* x){
    const float s = 0.70710678118654752440f;
    cpx e0 = x[0] + x[4], e2 = x[0] - x[4];
    cpx e1 = x[2] + x[6], e3 = x[2] - x[6];
    cpx E0 = e0 + e1, E2 = e0 - e1;
    cpx j3 = INV ? cmpi(e3) : cmji(e3);
    cpx E1 = e2 + j3, E3 = e2 - j3;
    cpx o0 = x[1] + x[5], o2 = x[1] - x[5];
    cpx o1 = x[3] + x[7], o3 = x[3] - x[7];
    cpx O0 = o0 + o1, O2 = o0 - o1;
    cpx k3 = INV ? cmpi(o3) : cmji(o3);
    cpx O1 = o2 + k3, O3 = o2 - k3;
    cpx W1, W2, W3;
    if (!INV){
        W1 = s*(O1 + cmji(O1));
        W2 = cmji(O2);
        W3 = s*(cmji(O3) - O3);
    } else {
        W1 = s*(O1 + cmpi(O1));
        W2 = cmpi(O2);
        W3 = s*(cmpi(O3) - O3);
    }
    x[0] = E0 + O0;
    x[1] = E1 + W1;
    x[2] = E2 + W2;
    x[3] = E3 + W3;
}

// ---------------- 256-pt radix-4 DIF FFT on a contiguous LDS line, 64 thr/line ----------------
// Output left base-4 digit-reversed in LDS. HIN: input support [0,128). CROP: only
// natural outputs <128 produced (positions g,g+1 of each last-stage butterfly).
template<bool INV, bool HIN, bool CROP>
__device__ __forceinline__ void fft256_r4(cpx* sl, int b){
    cpx x[4];
    {   // stage 0: stride 64, tw W_512^{2*j*r}
        int j = b;
        if (HIN){
            x[0] = sl[j]; x[1] = sl[j + 64];
            dft4_h2<INV>(x);
        } else {
            #pragma unroll
            for (int t = 0; t < 4; ++t) x[t] = sl[j + (t << 6)];
            dft4<INV>(x);
        }
        #pragma unroll
        for (int r = 1; r < 4; ++r) x[r] = twmul<INV>(x[r], 2*j*r);
        #pragma unroll
        for (int r = 0; r < 4; ++r) sl[j + (r << 6)] = x[r];
    }
    __syncthreads();
    {   // stage 1: stride 16, tw W_512^{8*j*r}
        int j = b & 15, g = (b >> 4) << 6;
        #pragma unroll
        for (int t = 0; t < 4; ++t) x[t] = sl[g + j + (t << 4)];
        dft4<INV>(x);
        #pragma unroll
        for (int r = 1; r < 4; ++r) x[r] = twmul<INV>(x[r], 8*j*r);
        #pragma unroll
        for (int r = 0; r < 4; ++r) sl[g + j + (r << 4)] = x[r];
    }
    __syncthreads();
    {   // stage 2: stride 4, tw W_512^{32*j*r}
        int j = b & 3, g = (b >> 2) << 4;
        #pragma unroll
        for (int t = 0; t < 4; ++t) x[t] = sl[g + j + (t << 2)];
        dft4<INV>(x);
        #pragma unroll
        for (int r = 1; r < 4; ++r) x[r] = twmul<INV>(x[r], 32*j*r);
        #pragma unroll
        for (int r = 0; r < 4; ++r) sl[g + j + (r << 2)] = x[r];
    }
    __syncthreads();
    {   // stage 3: stride 1, no twiddle
        int g = b << 2;
        #pragma unroll
        for (int t = 0; t < 4; ++t) x[t] = sl[g + t];
        if (CROP){
            dft4_lo2<INV>(x);
            sl[g] = x[0]; sl[g + 1] = x[1];
        } else {
            dft4<INV>(x);
            #pragma unroll
            for (int r = 0; r < 4; ++r) sl[g + r] = x[r];
        }
    }
    __syncthreads();
}

// ---------------- forward x-FFT fused with fill; store x-fftshifted AND x-half-blurred ----------------
// 4 lines/block. Stored position p gets 0.5*(F_s[p-1]+F_s[p]); F_s[q] = bin(q^128), F_s[-1]=0.
__global__ __launch_bounds__(256) void k_fft_x_fill(const float* __restrict__ feat, cpx* __restrict__ V){
    __shared__ cpx s[4*256];                     // 8 KiB
    int tid = threadIdx.x;
    int line0 = blockIdx.x << 2;                 // line = z*128 + y, z<256, y<128
    {
        int l = tid >> 6, e2 = tid & 63;         // one float2 of feat per thread
        int line = line0 + l;
        int z = line >> 7;
        float g = (float)z*(1.0f/255.0f);
        float2 v = ((const float2*)(feat + ((size_t)line << 7)))[e2];
        float a = v.x*g*g, bb = v.y*g*g;
        a  = a  > 0.0f ? sqrtf(a)  : 0.0f;
        bb = bb > 0.0f ? sqrtf(bb) : 0.0f;
        cpx* sl = s + l*256;
        sl[2*e2]     = (cpx){a, 0.0f};
        sl[2*e2 + 1] = (cpx){bb, 0.0f};
    }
    __syncthreads();
    fft256_r4<false, true, false>(s + (tid >> 6)*256, tid & 63);
    // blurred shifted store: F_s[e] sits at LDS pos rev4_8(e)^2 (rev4_8(128)=2)
    for (int i = tid; i < 4*128; i += 256){
        int l = i >> 7, f4 = i & 127;
        int line = line0 + l;
        int base = ((line >> 7) << 16) + ((line & 127) << 8);
        const cpx* sl = s + l*256;
        int e0 = 2*f4;
        cpx Fm = e0 ? sl[rev4_8(e0 - 1) ^ 2] : (cpx){0.0f, 0.0f};
        cpx F0 = sl[rev4_8(e0) ^ 2];
        cpx F1 = sl[rev4_8(e0 + 1) ^ 2];
        cpx o0 = 0.5f*(Fm + F0);
        cpx o1 = 0.5f*(F0 + F1);
        float4 o = make_float4(o0.x, o0.y, o1.x, o1.y);
        ((float4*)(V + base))[f4] = o;
    }
}

// ---------------- final inverse x-FFT fused with |.|^2, crop x<128; 4 lines/block ----------------
__global__ __launch_bounds__(256) void k_fft_x_inv_mag(const cpx* __restrict__ W,
                                                       float* __restrict__ out){
    __shared__ cpx s[4*256];                     // 8 KiB
    int tid = threadIdx.x;
    int line0 = blockIdx.x << 2;
    for (int i = tid; i < 4*128; i += 256){      // load 2 cpx per iteration
        int l = i >> 7, f4 = i & 127;
        int line = line0 + l;
        int base = ((line >> 7) << 16) + ((line & 127) << 8);
        ((float4*)(s + l*256))[f4] = ((const float4*)(W + base))[f4];
    }
    __syncthreads();
    fft256_r4<true, false, true>(s + (tid >> 6)*256, tid & 63);
    {
        int l = tid >> 6, e2 = tid & 63;         // two outputs per thread
        int line = line0 + l;
        int z = line >> 7, y = line & 127;
        const cpx* sl = s + l*256;
        cpx v0 = sl[rev4_8(2*e2)];
        cpx v1 = sl[rev4_8(2*e2 + 1)];
        const float SC2 = (1.0f/33554432.0f)*(1.0f/33554432.0f);   // (1/(512*256*256))^2
        float2 o = make_float2((v0.x*v0.x + v0.y*v0.y)*SC2,
                               (v1.x*v1.x + v1.y*v1.y)*SC2);
        ((float2*)(out + (((size_t)(z*128 + y)) << 7)))[e2] = o;
    }
}

// ---------------- FFT along y: 256 pts = 4 radix-4 DIF stages, tile 16 x, fixed z ----------------
// Forward (HALF_IN): stage-0 dft4_h2, no zero-fill; store y-fftshifted AND y-blurred.
// Inverse (HALF_OUT): stage-3 dft4_lo2, crop y<128.
template<bool INV, bool HALF_IN, bool HALF_OUT>
__global__ __launch_bounds__(1024) void k_fft_y(cpx* __restrict__ V){
    __shared__ cpx s[256*16];                   // 32 KiB
    int tid = threadIdx.x;
    int z  = blockIdx.x >> 4;
    int x0 = (blockIdx.x & 15) << 4;
    int base = (z << 16) + x0;
    const int YIN = HALF_IN ? 128 : 256;
    for (int i = tid; i < YIN*8; i += 1024){     // float4: 8 units of 2 cpx per row
        int f4c = i & 7, e = i >> 3;
        ((float4*)(s + e*16))[f4c] = ((const float4*)(V + base + (e << 8)))[f4c];
    }
    __syncthreads();
    int c = tid & 15, idx = tid >> 4;
    cpx x[4];
    {   // stage 0: stride 64, tw W_512^{2*j*r}
        int j = idx;
        if (HALF_IN){
            x[0] = s[j*16 + c]; x[1] = s[(j + 64)*16 + c];
            dft4_h2<INV>(x);
        } else {
            #pragma unroll
            for (int t = 0; t < 4; ++t) x[t] = s[(j + (t << 6))*16 + c];
            dft4<INV>(x);
        }
        #pragma unroll
        for (int r = 1; r < 4; ++r) x[r] = twmul<INV>(x[r], 2*j*r);
        #pragma unroll
        for (int r = 0; r < 4; ++r) s[(j + (r << 6))*16 + c] = x[r];
    }
    __syncthreads();
    {   // stage 1: stride 16, tw W_512^{8*j*r}
        int j = idx & 15, g = (idx >> 4) << 6;
        #pragma unroll
        for (int t = 0; t < 4; ++t) x[t] = s[(g + j + (t << 4))*16 + c];
        dft4<INV>(x);
        #pragma unroll
        for (int r = 1; r < 4; ++r) x[r] = twmul<INV>(x[r], 8*j*r);
        #pragma unroll
        for (int r = 0; r < 4; ++r) s[(g + j + (r << 4))*16 + c] = x[r];
    }
    __syncthreads();
    {   // stage 2: stride 4, tw W_512^{32*j*r}
        int j = idx & 3, g = (idx >> 2) << 4;
        #pragma unroll
        for (int t = 0; t < 4; ++t) x[t] = s[(g + j + (t << 2))*16 + c];
        dft4<INV>(x);
        #pragma unroll
        for (int r = 1; r < 4; ++r) x[r] = twmul<INV>(x[r], 32*j*r);
        #pragma unroll
        for (int r = 0; r < 4; ++r) s[(g + j + (r << 2))*16 + c] = x[r];
    }
    __syncthreads();
    {   // stage 3: stride 1, no twiddle
        int g = idx << 2;
        #pragma unroll
        for (int t = 0; t < 4; ++t) x[t] = s[(g + t)*16 + c];
        if (HALF_OUT){
            dft4_lo2<INV>(x);                    // only natural <128 needed
            s[g*16 + c] = x[0]; s[(g + 1)*16 + c] = x[1];
        } else {
            dft4<INV>(x);
            #pragma unroll
            for (int r = 0; r < 4; ++r) s[(g + r)*16 + c] = x[r];
        }
    }
    __syncthreads();
    const int YOUT = HALF_OUT ? 128 : 256;
    for (int i = tid; i < YOUT*8; i += 1024){
        int f4c = i & 7, e = i >> 3;
        if (!INV){
            // blurred shifted store: pos e = 0.5*(F_s[e-1] + F_s[e]); F_s[q] at row rev4(q)^2
            int p0 = rev4_8(e) ^ 2;
            float4 S0 = ((const float4*)(s + p0*16))[f4c];
            float4 S1 = make_float4(0.0f, 0.0f, 0.0f, 0.0f);
            if (e){
                int p1 = rev4_8(e - 1) ^ 2;
                S1 = ((const float4*)(s + p1*16))[f4c];
            }
            float4 o;
            o.x = 0.5f*(S0.x + S1.x); o.y = 0.5f*(S0.y + S1.y);
            o.z = 0.5f*(S0.z + S1.z); o.w = 0.5f*(S0.w + S1.w);
            ((float4*)(V + base + (e << 8)))[f4c] = o;
        } else {
            int p = rev4_8(e);
            ((float4*)(V + base + (e << 8)))[f4c] = ((const float4*)(s + p*16))[f4c];
        }
    }
}

// ---------------- forward FFT along z: 3 radix-8 DIF stages, tile 16 x, fixed y ----------------
// Input support planes 0..255 (stage-0 dft8_h4); output bins 0..255 only (stage-2
// dft8_lo4) stored at planes 256..511 (shifted).
__global__ __launch_bounds__(1024) void k_fft_z_fwd(cpx* __restrict__ V){
    __shared__ cpx s[512*16];                   // 64 KiB
    int tid = threadIdx.x;
    int y  = blockIdx.x >> 4;
    int x0 = (blockIdx.x & 15) << 4;
    int base = (y << 8) + x0;
    for (int i = tid; i < 256*8; i += 1024){
        int f4c = i & 7, e = i >> 3;
        ((float4*)(s + e*16))[f4c] = ((const float4*)(V + base + (e << 16)))[f4c];
    }
    __syncthreads();
    int c = tid & 15, idx = tid >> 4;
    cpx x[8];
    {   // stage 0: stride 64, inputs rows j+64t (t<4 nonzero), tw W_512^{j*r}
        int j = idx;
        #pragma unroll
        for (int t = 0; t < 4; ++t) x[t] = s[(j + (t << 6))*16 + c];
        dft8_h4<false>(x);
        #pragma unroll
        for (int r = 1; r < 8; ++r) x[r] = twmul<false>(x[r], j*r);
        #pragma unroll
        for (int r = 0; r < 8; ++r) s[(j + (r << 6))*16 + c] = x[r];
    }
    __syncthreads();
    {   // stage 1: stride 8, tw W_512^{8*j*r}
        int j = idx & 7, g = (idx >> 3) << 6;
        #pragma unroll
        for (int t = 0; t < 8; ++t) x[t] = s[(g + j + (t << 3))*16 + c];
        dft8<false>(x);
        #pragma unroll
        for (int r = 1; r < 8; ++r) x[r] = twmul<false>(x[r], 8*j*r);
        #pragma unroll
        for (int r = 0; r < 8; ++r) s[(g + j + (r << 3))*16 + c] = x[r];
    }
    __syncthreads();
    {   // stage 2: stride 1, no twiddle; only '+'-half outputs needed (pos bit2=0)
        int g = idx << 3;
        #pragma unroll
        for (int t = 0; t < 8; ++t) x[t] = s[(g + t)*16 + c];
        dft8_lo4<false>(x);
        #pragma unroll
        for (int r = 0; r < 4; ++r) s[(g + r)*16 + c] = x[r];
    }
    __syncthreads();
    for (int i = tid; i < 256*8; i += 1024){
        int f4c = i & 7, e = i >> 3;
        int p = ((e & 7) << 6) | (e & 56) | (e >> 6);   // base-8 digit reversal (bit2 always 0)
        ((float4*)(V + base + ((e + 256) << 16)))[f4c] = ((const float4*)(s + p*16))[f4c];
    }
}

// ---------------- FUSED: LDS-staged z-only Stolt gather + inverse z-FFT ----------------
// Stage A: coalesced load of partner source column planes 256..511 -> LDS rows 256..511.
// Stage B: z-interp gather from LDS rows >=256 (iz0>=256 for all zd>=1) into rows 0..255.
// Then inverse 512-pt FFT in place (stage-0 dft8_h4 reads rows 0..255 only, writes all;
// stage-2 dft8_lo4 crop z<256). Write planes 0..255.
__global__ __launch_bounds__(1024) void k_stolt_fftz_inv(const cpx* __restrict__ Vsrc, cpx* __restrict__ V){
    __shared__ cpx s[512*16];                   // 64 KiB
    int tid = threadIdx.x;
    int y  = blockIdx.x >> 4;
    int x0 = (blockIdx.x & 15) << 4;
    int base = (y << 8) + x0;
    int ys  = (y + 128) & 255;
    int xs0 = (x0 + 128) & 255;                 // 16-aligned, no wrap within tile
    int srcbase = (ys << 8) + xs0;
    // stage A: coalesced float4 load of source column planes 256..511 into rows 256..511
    for (int i = tid; i < 256*8; i += 1024){
        int f4c = i & 7, e = (i >> 3) + 256;
        ((float4*)(s + e*16))[f4c] = ((const float4*)(Vsrc + (((size_t)e) << 16) + srcbase))[f4c];
    }
    __syncthreads();
    // stage B: z-only gather from LDS rows >=256 into rows 0..255 (disjoint, race-free)
    int c = tid & 15;
    float gx = (float)(xs0 + c - 128)*(1.0f/128.0f);
    float gy = (float)(ys - 128)*(1.0f/128.0f);
    float rxy = 0.1024f*(gx*gx + gy*gy);
    #pragma unroll 4
    for (int i = tid; i < 256*16; i += 1024){
        int zd = i >> 4;
        cpx r = (cpx){0.0f, 0.0f};
        if (zd){
            float gz = (float)zd*(1.0f/256.0f);
            float gzn = sqrtf(rxy + gz*gz);
            float iz = ((gzn + 1.0f)*512.0f - 1.0f)*0.5f;
            float fiz = floorf(iz);
            int iz0 = (int)fiz;                  // in [256, ~536)
            float fz = iz - fiz;
            float sc = gz/(gzn + 1e-8f);
            int z0 = iz0 < 511 ? iz0 : 511;
            int z1 = (iz0 + 1) < 511 ? (iz0 + 1) : 511;
            float w0 = (iz0     <= 511) ? (1.0f - fz)*sc : 0.0f;
            float w1 = (iz0 + 1 <= 511) ? fz*sc : 0.0f;
            cpx a = s[(z0 << 4) + c];
            cpx b = s[(z1 << 4) + c];
            r = a*w0 + b*w1;
        }
        s[i] = r;                                // row zd < 256
    }
    __syncthreads();
    int idx = tid >> 4;
    cpx x[8];
    {   // stage 0: inputs rows j+64t (t<4 nonzero), tw W_512^{-j*r}; writes all 512 rows
        int j = idx;
        #pragma unroll
        for (int t = 0; t < 4; ++t) x[t] = s[(j + (t << 6))*16 + c];
        dft8_h4<true>(x);
        #pragma unroll
        for (int r = 1; r < 8; ++r) x[r] = twmul<true>(x[r], j*r);
        #pragma unroll
        for (int r = 0; r < 8; ++r) s[(j + (r << 6))*16 + c] = x[r];
    }
    __syncthreads();
    {   // stage 1
        int j = idx & 7, g = (idx >> 3) << 6;
        #pragma unroll
        for (int t = 0; t < 8; ++t) x[t] = s[(g + j + (t << 3))*16 + c];
        dft8<true>(x);
        #pragma unroll
        for (int r = 1; r < 8; ++r) x[r] = twmul<true>(x[r], 8*j*r);
        #pragma unroll
        for (int r = 0; r < 8; ++r) s[(g + j + (r << 3))*16 + c] = x[r];
    }
    __syncthreads();
    {   // stage 2: only '+'-half outputs needed (crop z<256, pos bit2=0)
        int g = idx << 3;
        #pragma unroll
        for (int t = 0; t < 8; ++t) x[t] = s[(g + t)*16 + c];
        dft8_lo4<true>(x);
        #pragma unroll
        for (int r = 0; r < 4; ++r) s[(g + r)*16 + c] = x[r];
    }
    __syncthreads();
    for (int i = tid; i < 256*8; i += 1024){
        int f4c = i & 7, e = i >> 3;
        int p = ((e & 7) << 6) | (e & 56) | (e >> 6);   // bit2 always 0
        ((float4*)(V + base + (e << 16)))[f4c] = ((const float4*)(s + p*16))[f4c];
    }
}

extern "C" void kernel_launch(void* const* d_in, const int* in_sizes, int n_in,
                              void* d_out, int out_size, void* d_ws, size_t ws_size,
                              hipStream_t stream){
    const float* feat = (const float*)d_in[0];   // [1,1,256,128,128] f32; tbes=0, tens=256
    float* out = (float*)d_out;                  // [1,1,256,128,128] f32

    const size_t WS_NEED = (size_t)512*256*256*8;   // 268,435,456 B exactly
    if (ws_size < WS_NEED){
        hipMemsetAsync(d_out, 0, (size_t)out_size*sizeof(float), stream);
        return;
    }
    cpx* V = (cpx*)d_ws;

    k_tw<<<1, 512, 0, stream>>>();
    // forward x (+fill,+x-blur) and y (+y-blur), stored fftshifted, planes 0..255
    k_fft_x_fill<<<8192, 256, 0, stream>>>(feat, V);                // 4 lines/block
    k_fft_y<false, true, false><<<4096, 1024, 0, stream>>>(V);      // z<256; y<128 in, blurred y out
    // z stage split (fusion variants lose to this — rounds 7/8)
    k_fft_z_fwd<<<4096, 1024, 0, stream>>>(V);                      // planes 0..255 -> 256..511
    k_stolt_fftz_inv<<<4096, 1024, 0, stream>>>(V, V);              // LDS-staged gather + inv z
    // inverse y + inverse x (+|.|^2) with crops
    k_fft_y<true, false, true><<<4096, 1024, 0, stream>>>(V);       // full y in, y<128 out
    k_fft_x_inv_mag<<<8192, 256, 0, stream>>>(V, out);              // 4 lines/block, |.|^2, x<128
}

// Round 13
// 264.428 us; speedup vs baseline: 1.0557x; 1.0557x over previous
//
#include <hip/hip_runtime.h>

// LCT FK-migration: 3D FFT(512,256,256) -> Stolt trilinear resample -> 3D IFFT -> |.|^2
// Single 256 MiB workspace buffer V = [512][256][256] cpx, flat (z<<16)+(y<<8)+x.
// x/y spectra stored FFTSHIFTED with the half-pixel Stolt x/y blurs folded into the
// forward x/y FFT stores (ix = xs-0.5, iy = ys-0.5 exactly => fx=fy=0.5 fixed blur).
// Z-stage SPLIT (fusion lost — rounds 7/8): k_fft_z_fwd writes shifted z-spectrum to
// planes 256..511; k_stolt_fftz_inv does the z-only gather + inverse z-FFT into planes
// 0..255. Inverse y (crop y<128) and inverse x + |.|^2 (crop x<128) finish.
// Round-13: FFT stage-0 is computed DIRECTLY FROM GLOBAL (coalesced 128B+ segments per
// wave) into registers in every kernel — removes one load phase + one barrier + 64KB
// LDS round-trip per block (stolt: barriers 5->3, gather fused into stage 0).
// Complex algebra as ext_vector<2 x float> for packed v_pk_*_f32 (VOP3P).
// Twiddles stored as float4 (c, c, -s, s): cmul(a,w) = a*wl + swap(a)*wh.

typedef float __attribute__((ext_vector_type(2))) cpx;

__device__ float4 g_tw4[512];   // (c, c, -s, s), (c,s) = exp(-2*pi*i*k/512)

__device__ __forceinline__ cpx cswap(cpx a){ return __builtin_shufflevector(a, a, 1, 0); }
// -i*a = (a.y, -a.x)
__device__ __forceinline__ cpx cmji(cpx a){ return cswap(a)*(cpx){1.0f, -1.0f}; }
// +i*a = (-a.y, a.x)
__device__ __forceinline__ cpx cmpi(cpx a){ return cswap(a)*(cpx){-1.0f, 1.0f}; }

// base-4 digit reversal of an 8-bit index
__device__ __forceinline__ int rev4_8(int k){
    return ((k & 3) << 6) | ((k & 12) << 2) | ((k >> 2) & 12) | (k >> 6);
}

// ---------------- twiddle table (double-computed for accuracy) ----------------
__global__ void k_tw(){
    int j = threadIdx.x;                        // 512 threads
    double a = -2.0*3.14159265358979323846*(double)j/512.0;
    float c = (float)cos(a), s = (float)sin(a);
    g_tw4[j] = make_float4(c, c, -s, s);
}

template<bool INV>
__device__ __forceinline__ cpx twmul(cpx a, int k){
    float4 t = g_tw4[k & 511];
    cpx wl = {t.x, t.y};                        // (c, c)
    cpx wh = {t.z, t.w};                        // (-s, s)
    cpx r = a*wl;
    return INV ? (r - cswap(a)*wh) : (r + cswap(a)*wh);
}

// ---------------- radix-4 DIF butterfly (packed, in-register), full ----------------
template<bool INV>
__device__ __forceinline__ void dft4(cpx* x){
    cpx e0 = x[0] + x[2], e1 = x[0] - x[2];
    cpx o0 = x[1] + x[3], o1 = x[1] - x[3];
    x[0] = e0 + o0;
    x[2] = e0 - o0;
    cpx j1 = INV ? cmpi(o1) : cmji(o1);
    x[1] = e1 + j1;
    x[3] = e1 - j1;
}

// radix-4 with x[2]=x[3]=0 (half-support input): inputs in x[0],x[1]
template<bool INV>
__device__ __forceinline__ void dft4_h2(cpx* x){
    cpx a0 = x[0], a1 = x[1];
    x[0] = a0 + a1;
    x[2] = a0 - a1;
    cpx j1 = INV ? cmpi(a1) : cmji(a1);
    x[1] = a0 + j1;
    x[3] = a0 - j1;
}

// radix-4 computing only outputs 0,1 (the '+' half)
template<bool INV>
__device__ __forceinline__ void dft4_lo2(cpx* x){
    cpx e0 = x[0] + x[2], e1 = x[0] - x[2];
    cpx o0 = x[1] + x[3], o1 = x[1] - x[3];
    x[0] = e0 + o0;
    x[1] = e1 + (INV ? cmpi(o1) : cmji(o1));
}

// ---------------- radix-8 DIF butterfly (packed, in-register), full ----------------
template<bool INV>
__device__ __forceinline__ void dft8(cpx* x){
    const float s = 0.70710678118654752440f;
    cpx e0 = x[0] + x[4], e2 = x[0] - x[4];
    cpx e1 = x[2] + x[6], e3 = x[2] - x[6];
    cpx E0 = e0 + e1, E2 = e0 - e1;
    cpx j3 = INV ? cmpi(e3) : cmji(e3);
    cpx E1 = e2 + j3, E3 = e2 - j3;
    cpx o0 = x[1] + x[5], o2 = x[1] - x[5];
    cpx o1 = x[3] + x[7], o3 = x[3] - x[7];
    cpx O0 = o0 + o1, O2 = o0 - o1;
    cpx k3 = INV ? cmpi(o3) : cmji(o3);
    cpx O1 = o2 + k3, O3 = o2 - k3;
    cpx W1, W2, W3;
    if (!INV){
        W1 = s*(O1 + cmji(O1));
        W2 = cmji(O2);
        W3 = s*(cmji(O3) - O3);
    } else {
        W1 = s*(O1 + cmpi(O1));
        W2 = cmpi(O2);
        W3 = s*(cmpi(O3) - O3);
    }
    x[0] = E0 + O0; x[4] = E0 - O0;
    x[1] = E1 + W1; x[5] = E1 - W1;
    x[2] = E2 + W2; x[6] = E2 - W2;
    x[3] = E3 + W3; x[7] = E3 - W3;
}

// radix-8 with x[4..7]=0: inputs in x[0..3], writes all 8 outputs
template<bool INV>
__device__ __forceinline__ void dft8_h4(cpx* x){
    const float s = 0.70710678118654752440f;
    cpx a0 = x[0], a1 = x[1], a2 = x[2], a3 = x[3];
    cpx E0 = a0 + a2, E2 = a0 - a2;
    cpx j3 = INV ? cmpi(a2) : cmji(a2);
    cpx E1 = a0 + j3, E3 = a0 - j3;
    cpx O0 = a1 + a3, O2 = a1 - a3;
    cpx k3 = INV ? cmpi(a3) : cmji(a3);
    cpx O1 = a1 + k3, O3 = a1 - k3;
    cpx W1, W2, W3;
    if (!INV){
        W1 = s*(O1 + cmji(O1));
        W2 = cmji(O2);
        W3 = s*(cmji(O3) - O3);
    } else {
        W1 = s*(O1 + cmpi(O1));
        W2 = cmpi(O2);
        W3 = s*(cmpi(O3) - O3);
    }
    x[0] = E0 + O0; x[4] = E0 - O0;
    x[1] = E1 + W1; x[5] = E1 - W1;
    x[2] = E2 + W2; x[6] = E2 - W2;
    x[3] = E3 + W3; x[7] = E3 - W3;
}

// radix-8 computing only outputs 0..3 (the '+' half)
template<bool INV>
__device__ __forceinline__ void dft8_lo4(cpx* x){
    const float s = 0.70710678118654752440f;
    cpx e0 = x[0] + x[4], e2 = x[0] - x[4];
    cpx e1 = x[2] + x[6], e3 = x[2] - x[6];
    cpx E0 = e0 + e1, E2 = e0 - e1;
    cpx j3 = INV ? cmpi(e3) : cmji(e3);
    cpx E1 = e2 + j3, E3 = e2 - j3;
    cpx o0 = x[1] + x[5], o2 = x[1] - x[5];
    cpx o1 = x[3] + x[7], o3 = x[3] - x[7];
    cpx O0 = o0 + o1, O2 = o0 - o1;
    cpx k3 = INV ? cmpi(o3) : cmji(o3);
    cpx O1 = o2 + k3, O3 = o2 - k3;
    cpx W1, W2, W3;
    if (!INV){
        W1 = s*(O1 + cmji(O1));
        W2 = cmji(O2);
        W3 = s*(cmji(O3) - O3);
    } else {
        W1 = s*(O1 + cmpi(O1));
        W2 = cmpi(O2);
        W3 = s*(cmpi(O3) - O3);
    }
    x[0] = E0 + O0;
    x[1] = E1 + W1;
    x[2] = E2 + W2;
    x[3] = E3 + W3;
}

// ---------------- 256-pt radix-4 FFT stages 1..3 on a contiguous LDS line ----------------
// Stage 0 is done by the caller (from global into registers). Output left base-4
// digit-reversed. CROP: only natural outputs <128 produced.
template<bool INV, bool CROP>
__device__ __forceinline__ void fft256_r4_tail(cpx* sl, int b){
    cpx x[4];
    {   // stage 1: stride 16, tw W_512^{8*j*r}
        int j = b & 15, g = (b >> 4) << 6;
        #pragma unroll
        for (int t = 0; t < 4; ++t) x[t] = sl[g + j + (t << 4)];
        dft4<INV>(x);
        #pragma unroll
        for (int r = 1; r < 4; ++r) x[r] = twmul<INV>(x[r], 8*j*r);
        #pragma unroll
        for (int r = 0; r < 4; ++r) sl[g + j + (r << 4)] = x[r];
    }
    __syncthreads();
    {   // stage 2: stride 4, tw W_512^{32*j*r}
        int j = b & 3, g = (b >> 2) << 4;
        #pragma unroll
        for (int t = 0; t < 4; ++t) x[t] = sl[g + j + (t << 2)];
        dft4<INV>(x);
        #pragma unroll
        for (int r = 1; r < 4; ++r) x[r] = twmul<INV>(x[r], 32*j*r);
        #pragma unroll
        for (int r = 0; r < 4; ++r) sl[g + j + (r << 2)] = x[r];
    }
    __syncthreads();
    {   // stage 3: stride 1, no twiddle
        int g = b << 2;
        #pragma unroll
        for (int t = 0; t < 4; ++t) x[t] = sl[g + t];
        if (CROP){
            dft4_lo2<INV>(x);
            sl[g] = x[0]; sl[g + 1] = x[1];
        } else {
            dft4<INV>(x);
            #pragma unroll
            for (int r = 0; r < 4; ++r) sl[g + r] = x[r];
        }
    }
    __syncthreads();
}

// ---------------- forward x-FFT fused with fill; store x-fftshifted AND x-half-blurred ----------------
// 4 lines/block. Stage 0 reads feat directly (window+sqrt applied in registers).
__global__ __launch_bounds__(256) void k_fft_x_fill(const float* __restrict__ feat, cpx* __restrict__ V){
    __shared__ cpx s[4*256];                     // 8 KiB
    int tid = threadIdx.x;
    int line0 = blockIdx.x << 2;                 // line = z*128 + y, z<256, y<128
    int l = tid >> 6, b = tid & 63;
    int line = line0 + l;
    cpx* sl = s + l*256;
    {   // stage 0 from global: inputs positions b, b+64 (support x<128)
        int z = line >> 7;
        float g = (float)z*(1.0f/255.0f);
        const float* fl = feat + ((size_t)line << 7);
        float a  = fl[b]*g*g;       a  = a  > 0.0f ? sqrtf(a)  : 0.0f;
        float bb = fl[b + 64]*g*g;  bb = bb > 0.0f ? sqrtf(bb) : 0.0f;
        cpx x[4];
        x[0] = (cpx){a, 0.0f};
        x[1] = (cpx){bb, 0.0f};
        dft4_h2<false>(x);
        #pragma unroll
        for (int r = 1; r < 4; ++r) x[r] = twmul<false>(x[r], 2*b*r);
        #pragma unroll
        for (int r = 0; r < 4; ++r) sl[b + (r << 6)] = x[r];
    }
    __syncthreads();
    fft256_r4_tail<false, false>(sl, b);
    // blurred shifted store: F_s[e] sits at LDS pos rev4_8(e)^2 (rev4_8(128)=2)
    for (int i = tid; i < 4*128; i += 256){
        int ll = i >> 7, f4 = i & 127;
        int lin = line0 + ll;
        int base = ((lin >> 7) << 16) + ((lin & 127) << 8);
        const cpx* sll = s + ll*256;
        int e0 = 2*f4;
        cpx Fm = e0 ? sll[rev4_8(e0 - 1) ^ 2] : (cpx){0.0f, 0.0f};
        cpx F0 = sll[rev4_8(e0) ^ 2];
        cpx F1 = sll[rev4_8(e0 + 1) ^ 2];
        cpx o0 = 0.5f*(Fm + F0);
        cpx o1 = 0.5f*(F0 + F1);
        float4 o = make_float4(o0.x, o0.y, o1.x, o1.y);
        ((float4*)(V + base))[f4] = o;
    }
}

// ---------------- final inverse x-FFT fused with |.|^2, crop x<128; 4 lines/block ----------------
__global__ __launch_bounds__(256) void k_fft_x_inv_mag(const cpx* __restrict__ W,
                                                       float* __restrict__ out){
    __shared__ cpx s[4*256];                     // 8 KiB
    int tid = threadIdx.x;
    int line0 = blockIdx.x << 2;
    int l = tid >> 6, b = tid & 63;
    int line = line0 + l;
    int base = ((line >> 7) << 16) + ((line & 127) << 8);
    cpx* sl = s + l*256;
    {   // stage 0 from global: rows b+64t, contiguous 512B per t across the 64 lanes
        cpx x[4];
        #pragma unroll
        for (int t = 0; t < 4; ++t) x[t] = W[base + b + (t << 6)];
        dft4<true>(x);
        #pragma unroll
        for (int r = 1; r < 4; ++r) x[r] = twmul<true>(x[r], 2*b*r);
        #pragma unroll
        for (int r = 0; r < 4; ++r) sl[b + (r << 6)] = x[r];
    }
    __syncthreads();
    fft256_r4_tail<true, true>(sl, b);
    {
        int z = line >> 7, y = line & 127;
        cpx v0 = sl[rev4_8(2*b)];
        cpx v1 = sl[rev4_8(2*b + 1)];
        const float SC2 = (1.0f/33554432.0f)*(1.0f/33554432.0f);   // (1/(512*256*256))^2
        float2 o = make_float2((v0.x*v0.x + v0.y*v0.y)*SC2,
                               (v1.x*v1.x + v1.y*v1.y)*SC2);
        ((float2*)(out + (((size_t)(z*128 + y)) << 7)))[b] = o;
    }
}

// ---------------- FFT along y: 256 pts = 4 radix-4 DIF stages, tile 16 x, fixed z ----------------
// Stage 0 from global (128B segments per wave). Forward (HALF_IN): dft4_h2; store
// y-fftshifted AND y-half-blurred. Inverse (HALF_OUT): stage-3 dft4_lo2, crop y<128.
template<bool INV, bool HALF_IN, bool HALF_OUT>
__global__ __launch_bounds__(1024) void k_fft_y(cpx* __restrict__ V){
    __shared__ cpx s[256*16];                   // 32 KiB
    int tid = threadIdx.x;
    int z  = blockIdx.x >> 4;
    int x0 = (blockIdx.x & 15) << 4;
    int base = (z << 16) + x0;
    int c = tid & 15, idx = tid >> 4;
    cpx x[4];
    {   // stage 0: rows idx+64t from global, tw W_512^{2*j*r}
        int j = idx;
        if (HALF_IN){
            x[0] = V[base + (j << 8) + c];
            x[1] = V[base + ((j + 64) << 8) + c];
            dft4_h2<INV>(x);
        } else {
            #pragma unroll
            for (int t = 0; t < 4; ++t) x[t] = V[base + ((j + (t << 6)) << 8) + c];
            dft4<INV>(x);
        }
        #pragma unroll
        for (int r = 1; r < 4; ++r) x[r] = twmul<INV>(x[r], 2*j*r);
        #pragma unroll
        for (int r = 0; r < 4; ++r) s[(j + (r << 6))*16 + c] = x[r];
    }
    __syncthreads();
    {   // stage 1: stride 16, tw W_512^{8*j*r}
        int j = idx & 15, g = (idx >> 4) << 6;
        #pragma unroll
        for (int t = 0; t < 4; ++t) x[t] = s[(g + j + (t << 4))*16 + c];
        dft4<INV>(x);
        #pragma unroll
        for (int r = 1; r < 4; ++r) x[r] = twmul<INV>(x[r], 8*j*r);
        #pragma unroll
        for (int r = 0; r < 4; ++r) s[(g + j + (r << 4))*16 + c] = x[r];
    }
    __syncthreads();
    {   // stage 2: stride 4, tw W_512^{32*j*r}
        int j = idx & 3, g = (idx >> 2) << 4;
        #pragma unroll
        for (int t = 0; t < 4; ++t) x[t] = s[(g + j + (t << 2))*16 + c];
        dft4<INV>(x);
        #pragma unroll
        for (int r = 1; r < 4; ++r) x[r] = twmul<INV>(x[r], 32*j*r);
        #pragma unroll
        for (int r = 0; r < 4; ++r) s[(g + j + (r << 2))*16 + c] = x[r];
    }
    __syncthreads();
    {   // stage 3: stride 1, no twiddle
        int g = idx << 2;
        #pragma unroll
        for (int t = 0; t < 4; ++t) x[t] = s[(g + t)*16 + c];
        if (HALF_OUT){
            dft4_lo2<INV>(x);                    // only natural <128 needed
            s[g*16 + c] = x[0]; s[(g + 1)*16 + c] = x[1];
        } else {
            dft4<INV>(x);
            #pragma unroll
            for (int r = 0; r < 4; ++r) s[(g + r)*16 + c] = x[r];
        }
    }
    __syncthreads();
    const int YOUT = HALF_OUT ? 128 : 256;
    for (int i = tid; i < YOUT*8; i += 1024){
        int f4c = i & 7, e = i >> 3;
        if (!INV){
            // blurred shifted store: pos e = 0.5*(F_s[e-1] + F_s[e]); F_s[q] at row rev4(q)^2
            int p0 = rev4_8(e) ^ 2;
            float4 S0 = ((const float4*)(s + p0*16))[f4c];
            float4 S1 = make_float4(0.0f, 0.0f, 0.0f, 0.0f);
            if (e){
                int p1 = rev4_8(e - 1) ^ 2;
                S1 = ((const float4*)(s + p1*16))[f4c];
            }
            float4 o;
            o.x = 0.5f*(S0.x + S1.x); o.y = 0.5f*(S0.y + S1.y);
            o.z = 0.5f*(S0.z + S1.z); o.w = 0.5f*(S0.w + S1.w);
            ((float4*)(V + base + (e << 8)))[f4c] = o;
        } else {
            int p = rev4_8(e);
            ((float4*)(V + base + (e << 8)))[f4c] = ((const float4*)(s + p*16))[f4c];
        }
    }
}

// ---------------- forward FFT along z: 3 radix-8 DIF stages, tile 16 x, fixed y ----------------
// Stage 0 from global (rows idx+64t, planes 0..255; 128B segments per wave).
// Output bins 0..255 only (stage-2 dft8_lo4) stored at planes 256..511 (shifted).
__global__ __launch_bounds__(1024) void k_fft_z_fwd(cpx* __restrict__ V){
    __shared__ cpx s[512*16];                   // 64 KiB
    int tid = threadIdx.x;
    int y  = blockIdx.x >> 4;
    int x0 = (blockIdx.x & 15) << 4;
    int base = (y << 8) + x0;
    int c = tid & 15, idx = tid >> 4;
    cpx x[8];
    {   // stage 0: inputs planes idx+64t (t<4 nonzero), tw W_512^{j*r}
        int j = idx;
        #pragma unroll
        for (int t = 0; t < 4; ++t)
            x[t] = V[base + (((size_t)(j + (t << 6))) << 16) + c];
        dft8_h4<false>(x);
        #pragma unroll
        for (int r = 1; r < 8; ++r) x[r] = twmul<false>(x[r], j*r);
        #pragma unroll
        for (int r = 0; r < 8; ++r) s[(j + (r << 6))*16 + c] = x[r];
    }
    __syncthreads();
    {   // stage 1: stride 8, tw W_512^{8*j*r}
        int j = idx & 7, g = (idx >> 3) << 6;
        #pragma unroll
        for (int t = 0; t < 8; ++t) x[t] = s[(g + j + (t << 3))*16 + c];
        dft8<false>(x);
        #pragma unroll
        for (int r = 1; r < 8; ++r) x[r] = twmul<false>(x[r], 8*j*r);
        #pragma unroll
        for (int r = 0; r < 8; ++r) s[(g + j + (r << 3))*16 + c] = x[r];
    }
    __syncthreads();
    {   // stage 2: stride 1, no twiddle; only '+'-half outputs needed (pos bit2=0)
        int g = idx << 3;
        #pragma unroll
        for (int t = 0; t < 8; ++t) x[t] = s[(g + t)*16 + c];
        dft8_lo4<false>(x);
        #pragma unroll
        for (int r = 0; r < 4; ++r) s[(g + r)*16 + c] = x[r];
    }
    __syncthreads();
    for (int i = tid; i < 256*8; i += 1024){
        int f4c = i & 7, e = i >> 3;
        int p = ((e & 7) << 6) | (e & 56) | (e >> 6);   // base-8 digit reversal (bit2 always 0)
        ((float4*)(V + base + ((e + 256) << 16)))[f4c] = ((const float4*)(s + p*16))[f4c];
    }
}

// ---------------- z-only Stolt gather from the HBM fwd spectrum (planes 256..511) ----------------
__device__ __forceinline__ cpx zgather_g(const cpx* __restrict__ Vsrc, int zd, float rxy, int srcoff){
    if (!zd) return (cpx){0.0f, 0.0f};           // t[:, :M+1] = 0 plane
    float gz = (float)zd*(1.0f/256.0f);
    float gzn = sqrtf(rxy + gz*gz);
    float iz = ((gzn + 1.0f)*512.0f - 1.0f)*0.5f;
    float fiz = floorf(iz);
    int iz0 = (int)fiz;                          // in [256, ~536)
    float fz = iz - fiz;
    float sc = gz/(gzn + 1e-8f);
    int z0 = iz0 < 511 ? iz0 : 511;
    int z1 = (iz0 + 1) < 511 ? (iz0 + 1) : 511;
    float w0 = (iz0     <= 511) ? (1.0f - fz)*sc : 0.0f;
    float w1 = (iz0 + 1 <= 511) ? fz*sc : 0.0f;
    cpx a = Vsrc[((size_t)z0 << 16) + srcoff];
    cpx b = Vsrc[((size_t)z1 << 16) + srcoff];
    return a*w0 + b*w1;
}

// ---------------- FUSED: z-only Stolt gather INSIDE stage 0 + inverse z-FFT ----------------
// Thread (c,idx) gathers zd = idx+64t (t<4) directly from global into stage-0 registers
// (8 independent coalesced 128B-segment loads in flight), then dft8_h4 + twiddles write
// the first LDS touch. Barriers: 3. Crop z<256 via stage-2 dft8_lo4. Write planes 0..255.
__global__ __launch_bounds__(1024) void k_stolt_fftz_inv(const cpx* __restrict__ Vsrc, cpx* __restrict__ V){
    __shared__ cpx s[512*16];                   // 64 KiB
    int tid = threadIdx.x;
    int y  = blockIdx.x >> 4;
    int x0 = (blockIdx.x & 15) << 4;
    int base = (y << 8) + x0;
    int c = tid & 15, idx = tid >> 4;
    int xs = ((x0 + c) + 128) & 255;
    int ys = (y + 128) & 255;
    float gx = (float)(xs - 128)*(1.0f/128.0f);
    float gy = (float)(ys - 128)*(1.0f/128.0f);
    float rxy = 0.1024f*(gx*gx + gy*gy);
    int srcoff = (ys << 8) + xs;
    cpx x[8];
    {   // stage 0: gather zd = idx+64t (t<4) from global, tw W_512^{-j*r}
        int j = idx;
        #pragma unroll
        for (int t = 0; t < 4; ++t)
            x[t] = zgather_g(Vsrc, j + (t << 6), rxy, srcoff);
        dft8_h4<true>(x);
        #pragma unroll
        for (int r = 1; r < 8; ++r) x[r] = twmul<true>(x[r], j*r);
        #pragma unroll
        for (int r = 0; r < 8; ++r) s[(j + (r << 6))*16 + c] = x[r];
    }
    __syncthreads();
    {   // stage 1
        int j = idx & 7, g = (idx >> 3) << 6;
        #pragma unroll
        for (int t = 0; t < 8; ++t) x[t] = s[(g + j + (t << 3))*16 + c];
        dft8<true>(x);
        #pragma unroll
        for (int r = 1; r < 8; ++r) x[r] = twmul<true>(x[r], 8*j*r);
        #pragma unroll
        for (int r = 0; r < 8; ++r) s[(g + j + (r << 3))*16 + c] = x[r];
    }
    __syncthreads();
    {   // stage 2: only '+'-half outputs needed (crop z<256, pos bit2=0)
        int g = idx << 3;
        #pragma unroll
        for (int t = 0; t < 8; ++t) x[t] = s[(g + t)*16 + c];
        dft8_lo4<true>(x);
        #pragma unroll
        for (int r = 0; r < 4; ++r) s[(g + r)*16 + c] = x[r];
    }
    __syncthreads();
    for (int i = tid; i < 256*8; i += 1024){
        int f4c = i & 7, e = i >> 3;
        int p = ((e & 7) << 6) | (e & 56) | (e >> 6);   // bit2 always 0
        ((float4*)(V + base + (e << 16)))[f4c] = ((const float4*)(s + p*16))[f4c];
    }
}

extern "C" void kernel_launch(void* const* d_in, const int* in_sizes, int n_in,
                              void* d_out, int out_size, void* d_ws, size_t ws_size,
                              hipStream_t stream){
    const float* feat = (const float*)d_in[0];   // [1,1,256,128,128] f32; tbes=0, tens=256
    float* out = (float*)d_out;                  // [1,1,256,128,128] f32

    const size_t WS_NEED = (size_t)512*256*256*8;   // 268,435,456 B exactly
    if (ws_size < WS_NEED){
        hipMemsetAsync(d_out, 0, (size_t)out_size*sizeof(float), stream);
        return;
    }
    cpx* V = (cpx*)d_ws;

    k_tw<<<1, 512, 0, stream>>>();
    // forward x (+fill,+x-blur) and y (+y-blur), stored fftshifted, planes 0..255
    k_fft_x_fill<<<8192, 256, 0, stream>>>(feat, V);                // 4 lines/block
    k_fft_y<false, true, false><<<4096, 1024, 0, stream>>>(V);      // z<256; y<128 in, blurred y out
    // z stage split (fusion variants lose to this — rounds 7/8)
    k_fft_z_fwd<<<4096, 1024, 0, stream>>>(V);                      // planes 0..255 -> 256..511
    k_stolt_fftz_inv<<<4096, 1024, 0, stream>>>(V, V);              // gather-in-stage0 + inv z
    // inverse y + inverse x (+|.|^2) with crops
    k_fft_y<true, false, true><<<4096, 1024, 0, stream>>>(V);       // full y in, y<128 out
    k_fft_x_inv_mag<<<8192, 256, 0, stream>>>(V, out);              // 4 lines/block, |.|^2, x<128
}

// Round 14
// 258.621 us; speedup vs baseline: 1.0794x; 1.0225x over previous
//
#include <hip/hip_runtime.h>

// LCT FK-migration: 3D FFT(512,256,256) -> Stolt trilinear resample -> 3D IFFT -> |.|^2
// Single 256 MiB workspace buffer V = [512][256][256] cpx, flat (z<<16)+(y<<8)+x.
// x/y spectra stored FFTSHIFTED with the half-pixel Stolt x/y blurs folded into the
// forward x/y FFT stores (ix = xs-0.5, iy = ys-0.5 exactly => fx=fy=0.5 fixed blur).
// Round-14: z-stage FUSED in one kernel (3rd attempt, now with lean machinery):
// block for dest column (y,x-tile) forward-FFTs its partner source column
// ((y+128)&255,(x+128)&255) — stage 0 straight from global (planes 0..255), h4/lo4
// half-butterflies, fwd bins stored at NATURAL rows in LDS — then z-only Stolt gather
// from LDS into inverse-stage-0 registers, inverse FFT, direct store to planes
// 256..511 (disjoint from all source reads -> race-free). 6 barriers total.
// Inverse y (crop y<128, direct reg->global store) and inverse x + |.|^2 (crop x<128)
// run on planes 256..511 via offset base pointer.
// Complex algebra as ext_vector<2 x float> for packed v_pk_*_f32 (VOP3P).
// Twiddles stored as float4 (c, c, -s, s): cmul(a,w) = a*wl + swap(a)*wh.

typedef float __attribute__((ext_vector_type(2))) cpx;

__device__ float4 g_tw4[512];   // (c, c, -s, s), (c,s) = exp(-2*pi*i*k/512)

__device__ __forceinline__ cpx cswap(cpx a){ return __builtin_shufflevector(a, a, 1, 0); }
// -i*a = (a.y, -a.x)
__device__ __forceinline__ cpx cmji(cpx a){ return cswap(a)*(cpx){1.0f, -1.0f}; }
// +i*a = (-a.y, a.x)
__device__ __forceinline__ cpx cmpi(cpx a){ return cswap(a)*(cpx){-1.0f, 1.0f}; }

// base-4 digit reversal of an 8-bit index
__device__ __forceinline__ int rev4_8(int k){
    return ((k & 3) << 6) | ((k & 12) << 2) | ((k >> 2) & 12) | (k >> 6);
}
// base-8 digit reversal of a 9-bit index
__device__ __forceinline__ int rev8_9(int k){
    return ((k & 7) << 6) | (k & 56) | (k >> 6);
}

// ---------------- twiddle table (double-computed for accuracy) ----------------
__global__ void k_tw(){
    int j = threadIdx.x;                        // 512 threads
    double a = -2.0*3.14159265358979323846*(double)j/512.0;
    float c = (float)cos(a), s = (float)sin(a);
    g_tw4[j] = make_float4(c, c, -s, s);
}

template<bool INV>
__device__ __forceinline__ cpx twmul(cpx a, int k){
    float4 t = g_tw4[k & 511];
    cpx wl = {t.x, t.y};                        // (c, c)
    cpx wh = {t.z, t.w};                        // (-s, s)
    cpx r = a*wl;
    return INV ? (r - cswap(a)*wh) : (r + cswap(a)*wh);
}

// ---------------- radix-4 DIF butterfly (packed, in-register), full ----------------
template<bool INV>
__device__ __forceinline__ void dft4(cpx* x){
    cpx e0 = x[0] + x[2], e1 = x[0] - x[2];
    cpx o0 = x[1] + x[3], o1 = x[1] - x[3];
    x[0] = e0 + o0;
    x[2] = e0 - o0;
    cpx j1 = INV ? cmpi(o1) : cmji(o1);
    x[1] = e1 + j1;
    x[3] = e1 - j1;
}

// radix-4 with x[2]=x[3]=0 (half-support input): inputs in x[0],x[1]
template<bool INV>
__device__ __forceinline__ void dft4_h2(cpx* x){
    cpx a0 = x[0], a1 = x[1];
    x[0] = a0 + a1;
    x[2] = a0 - a1;
    cpx j1 = INV ? cmpi(a1) : cmji(a1);
    x[1] = a0 + j1;
    x[3] = a0 - j1;
}

// radix-4 computing only outputs 0,1 (the '+' half)
template<bool INV>
__device__ __forceinline__ void dft4_lo2(cpx* x){
    cpx e0 = x[0] + x[2], e1 = x[0] - x[2];
    cpx o0 = x[1] + x[3], o1 = x[1] - x[3];
    x[0] = e0 + o0;
    x[1] = e1 + (INV ? cmpi(o1) : cmji(o1));
}

// ---------------- radix-8 DIF butterfly (packed, in-register), full ----------------
template<bool INV>
__device__ __forceinline__ void dft8(cpx* x){
    const float s = 0.70710678118654752440f;
    cpx e0 = x[0] + x[4], e2 = x[0] - x[4];
    cpx e1 = x[2] + x[6], e3 = x[2] - x[6];
    cpx E0 = e0 + e1, E2 = e0 - e1;
    cpx j3 = INV ? cmpi(e3) : cmji(e3);
    cpx E1 = e2 + j3, E3 = e2 - j3;
    cpx o0 = x[1] + x[5], o2 = x[1] - x[5];
    cpx o1 = x[3] + x[7], o3 = x[3] - x[7];
    cpx O0 = o0 + o1, O2 = o0 - o1;
    cpx k3 = INV ? cmpi(o3) : cmji(o3);
    cpx O1 = o2 + k3, O3 = o2 - k3;
    cpx W1, W2, W3;
    if (!INV){
        W1 = s*(O1 + cmji(O1));
        W2 = cmji(O2);
        W3 = s*(cmji(O3) - O3);
    } else {
        W1 = s*(O1 + cmpi(O1));
        W2 = cmpi(O2);
        W3 = s*(cmpi(O3) - O3);
    }
    x[0] = E0 + O0; x[4] = E0 - O0;
    x[1] = E1 + W1; x[5] = E1 - W1;
    x[2] = E2 + W2; x[6] = E2 - W2;
    x[3] = E3 + W3; x[7] = E3 - W3;
}

// radix-8 with x[4..7]=0: inputs in x[0..3], writes all 8 outputs
template<bool INV>
__device__ __forceinline__ void dft8_h4(cpx* x){
    const float s = 0.70710678118654752440f;
    cpx a0 = x[0], a1 = x[1], a2 = x[2], a3 = x[3];
    cpx E0 = a0 + a2, E2 = a0 - a2;
    cpx j3 = INV ? cmpi(a2) : cmji(a2);
    cpx E1 = a0 + j3, E3 = a0 - j3;
    cpx O0 = a1 + a3, O2 = a1 - a3;
    cpx k3 = INV ? cmpi(a3) : cmji(a3);
    cpx O1 = a1 + k3, O3 = a1 - k3;
    cpx W1, W2, W3;
    if (!INV){
        W1 = s*(O1 + cmji(O1));
        W2 = cmji(O2);
        W3 = s*(cmji(O3) - O3);
    } else {
        W1 = s*(O1 + cmpi(O1));
        W2 = cmpi(O2);
        W3 = s*(cmpi(O3) - O3);
    }
    x[0] = E0 + O0; x[4] = E0 - O0;
    x[1] = E1 + W1; x[5] = E1 - W1;
    x[2] = E2 + W2; x[6] = E2 - W2;
    x[3] = E3 + W3; x[7] = E3 - W3;
}

// radix-8 computing only outputs 0..3 (the '+' half)
template<bool INV>
__device__ __forceinline__ void dft8_lo4(cpx* x){
    const float s = 0.70710678118654752440f;
    cpx e0 = x[0] + x[4], e2 = x[0] - x[4];
    cpx e1 = x[2] + x[6], e3 = x[2] - x[6];
    cpx E0 = e0 + e1, E2 = e0 - e1;
    cpx j3 = INV ? cmpi(e3) : cmji(e3);
    cpx E1 = e2 + j3, E3 = e2 - j3;
    cpx o0 = x[1] + x[5], o2 = x[1] - x[5];
    cpx o1 = x[3] + x[7], o3 = x[3] - x[7];
    cpx O0 = o0 + o1, O2 = o0 - o1;
    cpx k3 = INV ? cmpi(o3) : cmji(o3);
    cpx O1 = o2 + k3, O3 = o2 - k3;
    cpx W1, W2, W3;
    if (!INV){
        W1 = s*(O1 + cmji(O1));
        W2 = cmji(O2);
        W3 = s*(cmji(O3) - O3);
    } else {
        W1 = s*(O1 + cmpi(O1));
        W2 = cmpi(O2);
        W3 = s*(cmpi(O3) - O3);
    }
    x[0] = E0 + O0;
    x[1] = E1 + W1;
    x[2] = E2 + W2;
    x[3] = E3 + W3;
}

// ---------------- 256-pt radix-4 FFT stages 1..3 on a contiguous LDS line ----------------
// Stage 0 is done by the caller (from global into registers). Output left base-4
// digit-reversed. CROP: only natural outputs <128 produced.
template<bool INV, bool CROP>
__device__ __forceinline__ void fft256_r4_tail(cpx* sl, int b){
    cpx x[4];
    {   // stage 1: stride 16, tw W_512^{8*j*r}
        int j = b & 15, g = (b >> 4) << 6;
        #pragma unroll
        for (int t = 0; t < 4; ++t) x[t] = sl[g + j + (t << 4)];
        dft4<INV>(x);
        #pragma unroll
        for (int r = 1; r < 4; ++r) x[r] = twmul<INV>(x[r], 8*j*r);
        #pragma unroll
        for (int r = 0; r < 4; ++r) sl[g + j + (r << 4)] = x[r];
    }
    __syncthreads();
    {   // stage 2: stride 4, tw W_512^{32*j*r}
        int j = b & 3, g = (b >> 2) << 4;
        #pragma unroll
        for (int t = 0; t < 4; ++t) x[t] = sl[g + j + (t << 2)];
        dft4<INV>(x);
        #pragma unroll
        for (int r = 1; r < 4; ++r) x[r] = twmul<INV>(x[r], 32*j*r);
        #pragma unroll
        for (int r = 0; r < 4; ++r) sl[g + j + (r << 2)] = x[r];
    }
    __syncthreads();
    {   // stage 3: stride 1, no twiddle
        int g = b << 2;
        #pragma unroll
        for (int t = 0; t < 4; ++t) x[t] = sl[g + t];
        if (CROP){
            dft4_lo2<INV>(x);
            sl[g] = x[0]; sl[g + 1] = x[1];
        } else {
            dft4<INV>(x);
            #pragma unroll
            for (int r = 0; r < 4; ++r) sl[g + r] = x[r];
        }
    }
    __syncthreads();
}

// ---------------- forward x-FFT fused with fill; store x-fftshifted AND x-half-blurred ----------------
// 4 lines/block. Stage 0 reads feat directly (window+sqrt applied in registers).
__global__ __launch_bounds__(256) void k_fft_x_fill(const float* __restrict__ feat, cpx* __restrict__ V){
    __shared__ cpx s[4*256];                     // 8 KiB
    int tid = threadIdx.x;
    int line0 = blockIdx.x << 2;                 // line = z*128 + y, z<256, y<128
    int l = tid >> 6, b = tid & 63;
    int line = line0 + l;
    cpx* sl = s + l*256;
    {   // stage 0 from global: inputs positions b, b+64 (support x<128)
        int z = line >> 7;
        float g = (float)z*(1.0f/255.0f);
        const float* fl = feat + ((size_t)line << 7);
        float a  = fl[b]*g*g;       a  = a  > 0.0f ? sqrtf(a)  : 0.0f;
        float bb = fl[b + 64]*g*g;  bb = bb > 0.0f ? sqrtf(bb) : 0.0f;
        cpx x[4];
        x[0] = (cpx){a, 0.0f};
        x[1] = (cpx){bb, 0.0f};
        dft4_h2<false>(x);
        #pragma unroll
        for (int r = 1; r < 4; ++r) x[r] = twmul<false>(x[r], 2*b*r);
        #pragma unroll
        for (int r = 0; r < 4; ++r) sl[b + (r << 6)] = x[r];
    }
    __syncthreads();
    fft256_r4_tail<false, false>(sl, b);
    // blurred shifted store: F_s[e] sits at LDS pos rev4_8(e)^2 (rev4_8(128)=2)
    for (int i = tid; i < 4*128; i += 256){
        int ll = i >> 7, f4 = i & 127;
        int lin = line0 + ll;
        int base = ((lin >> 7) << 16) + ((lin & 127) << 8);
        const cpx* sll = s + ll*256;
        int e0 = 2*f4;
        cpx Fm = e0 ? sll[rev4_8(e0 - 1) ^ 2] : (cpx){0.0f, 0.0f};
        cpx F0 = sll[rev4_8(e0) ^ 2];
        cpx F1 = sll[rev4_8(e0 + 1) ^ 2];
        cpx o0 = 0.5f*(Fm + F0);
        cpx o1 = 0.5f*(F0 + F1);
        float4 o = make_float4(o0.x, o0.y, o1.x, o1.y);
        ((float4*)(V + base))[f4] = o;
    }
}

// ---------------- final inverse x-FFT fused with |.|^2, crop x<128; 4 lines/block ----------------
__global__ __launch_bounds__(256) void k_fft_x_inv_mag(const cpx* __restrict__ W,
                                                       float* __restrict__ out){
    __shared__ cpx s[4*256];                     // 8 KiB
    int tid = threadIdx.x;
    int line0 = blockIdx.x << 2;
    int l = tid >> 6, b = tid & 63;
    int line = line0 + l;
    int base = ((line >> 7) << 16) + ((line & 127) << 8);
    cpx* sl = s + l*256;
    {   // stage 0 from global: rows b+64t, contiguous 512B per t across the 64 lanes
        cpx x[4];
        #pragma unroll
        for (int t = 0; t < 4; ++t) x[t] = W[base + b + (t << 6)];
        dft4<true>(x);
        #pragma unroll
        for (int r = 1; r < 4; ++r) x[r] = twmul<true>(x[r], 2*b*r);
        #pragma unroll
        for (int r = 0; r < 4; ++r) sl[b + (r << 6)] = x[r];
    }
    __syncthreads();
    fft256_r4_tail<true, true>(sl, b);
    {
        int z = line >> 7, y = line & 127;
        cpx v0 = sl[rev4_8(2*b)];
        cpx v1 = sl[rev4_8(2*b + 1)];
        const float SC2 = (1.0f/33554432.0f)*(1.0f/33554432.0f);   // (1/(512*256*256))^2
        float2 o = make_float2((v0.x*v0.x + v0.y*v0.y)*SC2,
                               (v1.x*v1.x + v1.y*v1.y)*SC2);
        ((float2*)(out + (((size_t)(z*128 + y)) << 7)))[b] = o;
    }
}

// ---------------- FFT along y: 256 pts = 4 radix-4 DIF stages, tile 16 x, fixed z ----------------
// Stage 0 from global (128B segments per wave). Forward (HALF_IN): dft4_h2; store
// y-fftshifted AND y-half-blurred. Inverse (HALF_OUT): stage-3 dft4_lo2 with DIRECT
// register->global store of bins rev4(g), rev4(g)+64 (crop y<128), no final barrier.
template<bool INV, bool HALF_IN, bool HALF_OUT>
__global__ __launch_bounds__(1024) void k_fft_y(cpx* __restrict__ V){
    __shared__ cpx s[256*16];                   // 32 KiB
    int tid = threadIdx.x;
    int z  = blockIdx.x >> 4;
    int x0 = (blockIdx.x & 15) << 4;
    int base = (z << 16) + x0;
    int c = tid & 15, idx = tid >> 4;
    cpx x[4];
    {   // stage 0: rows idx+64t from global, tw W_512^{2*j*r}
        int j = idx;
        if (HALF_IN){
            x[0] = V[base + (j << 8) + c];
            x[1] = V[base + ((j + 64) << 8) + c];
            dft4_h2<INV>(x);
        } else {
            #pragma unroll
            for (int t = 0; t < 4; ++t) x[t] = V[base + ((j + (t << 6)) << 8) + c];
            dft4<INV>(x);
        }
        #pragma unroll
        for (int r = 1; r < 4; ++r) x[r] = twmul<INV>(x[r], 2*j*r);
        #pragma unroll
        for (int r = 0; r < 4; ++r) s[(j + (r << 6))*16 + c] = x[r];
    }
    __syncthreads();
    {   // stage 1: stride 16, tw W_512^{8*j*r}
        int j = idx & 15, g = (idx >> 4) << 6;
        #pragma unroll
        for (int t = 0; t < 4; ++t) x[t] = s[(g + j + (t << 4))*16 + c];
        dft4<INV>(x);
        #pragma unroll
        for (int r = 1; r < 4; ++r) x[r] = twmul<INV>(x[r], 8*j*r);
        #pragma unroll
        for (int r = 0; r < 4; ++r) s[(g + j + (r << 4))*16 + c] = x[r];
    }
    __syncthreads();
    {   // stage 2: stride 4, tw W_512^{32*j*r}
        int j = idx & 3, g = (idx >> 2) << 4;
        #pragma unroll
        for (int t = 0; t < 4; ++t) x[t] = s[(g + j + (t << 2))*16 + c];
        dft4<INV>(x);
        #pragma unroll
        for (int r = 1; r < 4; ++r) x[r] = twmul<INV>(x[r], 32*j*r);
        #pragma unroll
        for (int r = 0; r < 4; ++r) s[(g + j + (r << 2))*16 + c] = x[r];
    }
    __syncthreads();
    if (HALF_OUT){
        // stage 3 + direct store: thread holds positions g,g+1 = bins rev4(g), rev4(g)+64
        int g = idx << 2;
        #pragma unroll
        for (int t = 0; t < 4; ++t) x[t] = s[(g + t)*16 + c];
        dft4_lo2<INV>(x);
        int e0 = rev4_8(g);                      // < 64
        V[base + (e0 << 8) + c] = x[0];
        V[base + ((e0 + 64) << 8) + c] = x[1];
        return;
    }
    {   // stage 3 full, then blurred shifted epilogue
        int g = idx << 2;
        #pragma unroll
        for (int t = 0; t < 4; ++t) x[t] = s[(g + t)*16 + c];
        dft4<INV>(x);
        #pragma unroll
        for (int r = 0; r < 4; ++r) s[(g + r)*16 + c] = x[r];
    }
    __syncthreads();
    for (int i = tid; i < 256*8; i += 1024){
        int f4c = i & 7, e = i >> 3;
        // blurred shifted store: pos e = 0.5*(F_s[e-1] + F_s[e]); F_s[q] at row rev4(q)^2
        int p0 = rev4_8(e) ^ 2;
        float4 S0 = ((const float4*)(s + p0*16))[f4c];
        float4 S1 = make_float4(0.0f, 0.0f, 0.0f, 0.0f);
        if (e){
            int p1 = rev4_8(e - 1) ^ 2;
            S1 = ((const float4*)(s + p1*16))[f4c];
        }
        float4 o;
        o.x = 0.5f*(S0.x + S1.x); o.y = 0.5f*(S0.y + S1.y);
        o.z = 0.5f*(S0.z + S1.z); o.w = 0.5f*(S0.w + S1.w);
        ((float4*)(V + base + (e << 8)))[f4c] = o;
    }
}

// ---------------- FUSED z-stage: fwd z-FFT (partner source column) + Stolt gather +
// inverse z-FFT, one 64 KiB buffer, 6 barriers. Reads planes 0..255 only; writes dest
// to planes 256..511 (disjoint -> race-free across blocks). ----------------
__global__ __launch_bounds__(1024, 8) void k_fftz_fused(cpx* __restrict__ V){
    __shared__ cpx s[512*16];                   // 64 KiB
    int tid = threadIdx.x;
    int yD  = blockIdx.x >> 4;
    int x0D = (blockIdx.x & 15) << 4;
    int baseD = (yD << 8) + x0D;
    int yS  = (yD + 128) & 255;
    int x0S = (x0D + 128) & 255;                // 16-aligned; x0S+c stays in tile
    int baseS = (yS << 8) + x0S;
    int c = tid & 15, idx = tid >> 4;
    cpx x[8];
    int j = idx;
    {   // fwd stage 0: source planes j+64t (t<4 nonzero) straight from global
        #pragma unroll
        for (int t = 0; t < 4; ++t)
            x[t] = V[baseS + (((size_t)(j + (t << 6))) << 16) + c];
        dft8_h4<false>(x);
        #pragma unroll
        for (int r = 1; r < 8; ++r) x[r] = twmul<false>(x[r], j*r);
        #pragma unroll
        for (int r = 0; r < 8; ++r) s[(j + (r << 6))*16 + c] = x[r];
    }
    __syncthreads();
    {   // fwd stage 1
        int jj = idx & 7, g = (idx >> 3) << 6;
        #pragma unroll
        for (int t = 0; t < 8; ++t) x[t] = s[(g + jj + (t << 3))*16 + c];
        dft8<false>(x);
        #pragma unroll
        for (int r = 1; r < 8; ++r) x[r] = twmul<false>(x[r], 8*jj*r);
        #pragma unroll
        for (int r = 0; r < 8; ++r) s[(g + jj + (r << 3))*16 + c] = x[r];
    }
    __syncthreads();
    {   // fwd stage 2 lo4: write bins 0..255 at NATURAL rows e = rev8(position)
        int g = idx << 3;
        #pragma unroll
        for (int t = 0; t < 8; ++t) x[t] = s[(g + t)*16 + c];
        dft8_lo4<false>(x);
        #pragma unroll
        for (int r = 0; r < 4; ++r){
            int e = (r << 6) | ((idx & 7) << 3) | (idx >> 3);   // rev8_9(g+r), < 256
            s[e*16 + c] = x[r];
        }
    }
    __syncthreads();
    // Stolt gather (dest coords = source position) -> inverse stage-0 registers
    {
        int xs = x0S + c;
        float gx = (float)(xs - 128)*(1.0f/128.0f);
        float gy = (float)(yS - 128)*(1.0f/128.0f);
        float rxy = 0.1024f*(gx*gx + gy*gy);
        #pragma unroll
        for (int t = 0; t < 4; ++t){
            int zd = j + (t << 6);
            cpx r = (cpx){0.0f, 0.0f};
            if (zd){
                float gz = (float)zd*(1.0f/256.0f);
                float gzn = sqrtf(rxy + gz*gz);
                float iz = ((gzn + 1.0f)*512.0f - 1.0f)*0.5f;
                float fiz = floorf(iz);
                int iz0 = (int)fiz;              // in [256, ~536)
                float fz = iz - fiz;
                float sc = gz/(gzn + 1e-8f);
                int b0 = (iz0 < 511 ? iz0 : 511) - 256;
                int b1 = ((iz0 + 1) < 511 ? (iz0 + 1) : 511) - 256;
                float w0 = (iz0     <= 511) ? (1.0f - fz)*sc : 0.0f;
                float w1 = (iz0 + 1 <= 511) ? fz*sc : 0.0f;
                cpx a = s[(b0 << 4) + c];        // natural-row fwd bins
                cpx b = s[(b1 << 4) + c];
                r = a*w0 + b*w1;
            }
            x[t] = r;
        }
        dft8_h4<true>(x);
        #pragma unroll
        for (int r = 1; r < 8; ++r) x[r] = twmul<true>(x[r], j*r);
    }
    __syncthreads();                             // all gather reads done before overwrite
    {
        #pragma unroll
        for (int r = 0; r < 8; ++r) s[(j + (r << 6))*16 + c] = x[r];
    }
    __syncthreads();
    {   // inv stage 1
        int jj = idx & 7, g = (idx >> 3) << 6;
        #pragma unroll
        for (int t = 0; t < 8; ++t) x[t] = s[(g + jj + (t << 3))*16 + c];
        dft8<true>(x);
        #pragma unroll
        for (int r = 1; r < 8; ++r) x[r] = twmul<true>(x[r], 8*jj*r);
        #pragma unroll
        for (int r = 0; r < 8; ++r) s[(g + jj + (r << 3))*16 + c] = x[r];
    }
    __syncthreads();
    {   // inv stage 2 lo4 + DIRECT store of z<256 to dest planes 256..511
        int g = idx << 3;
        #pragma unroll
        for (int t = 0; t < 8; ++t) x[t] = s[(g + t)*16 + c];
        dft8_lo4<true>(x);
        #pragma unroll
        for (int r = 0; r < 4; ++r){
            int e = (r << 6) | ((idx & 7) << 3) | (idx >> 3);   // rev8_9(g+r), < 256
            V[baseD + (((size_t)(e + 256)) << 16) + c] = x[r];
        }
    }
}

extern "C" void kernel_launch(void* const* d_in, const int* in_sizes, int n_in,
                              void* d_out, int out_size, void* d_ws, size_t ws_size,
                              hipStream_t stream){
    const float* feat = (const float*)d_in[0];   // [1,1,256,128,128] f32; tbes=0, tens=256
    float* out = (float*)d_out;                  // [1,1,256,128,128] f32

    const size_t WS_NEED = (size_t)512*256*256*8;   // 268,435,456 B exactly
    if (ws_size < WS_NEED){
        hipMemsetAsync(d_out, 0, (size_t)out_size*sizeof(float), stream);
        return;
    }
    cpx* V  = (cpx*)d_ws;
    cpx* Vu = V + (size_t)256*65536;             // planes 256..511 (post-z result)

    k_tw<<<1, 512, 0, stream>>>();
    // forward x (+fill,+x-blur) and y (+y-blur), stored fftshifted, planes 0..255
    k_fft_x_fill<<<8192, 256, 0, stream>>>(feat, V);                // 4 lines/block
    k_fft_y<false, true, false><<<4096, 1024, 0, stream>>>(V);      // z<256; y<128 in, blurred y out
    // fused z-stage: fwd FFT of partner column + gather + inv FFT -> planes 256..511
    k_fftz_fused<<<4096, 1024, 0, stream>>>(V);
    // inverse y + inverse x (+|.|^2) on planes 256..511 via offset base pointer
    k_fft_y<true, false, true><<<4096, 1024, 0, stream>>>(Vu);      // full y in, y<128 out (direct store)
    k_fft_x_inv_mag<<<8192, 256, 0, stream>>>(Vu, out);             // 4 lines/block, |.|^2, x<128
}

// Round 15
// 246.138 us; speedup vs baseline: 1.1342x; 1.0507x over previous
//
#include <hip/hip_runtime.h>

// LCT FK-migration: 3D FFT(512,256,256) -> Stolt trilinear resample -> 3D IFFT -> |.|^2
// Single 256 MiB workspace buffer V = [512][256][256] cpx, flat (z<<16)+(y<<8)+x.
// x/y spectra stored FFTSHIFTED with the half-pixel Stolt x/y blurs folded into the
// forward x/y FFT stores (ix = xs-0.5, iy = ys-0.5 exactly => fx=fy=0.5 fixed blur).
// Z-stage FUSED (k_fftz_fused, round-14): block for dest column (y,x-tile) fwd-FFTs its
// partner source column ((y+128)&255,(x+128)&255) — stage 0 straight from global,
// h4/lo4 half-butterflies, fwd bins at NATURAL LDS rows — then z-only Stolt gather from
// LDS into inverse-stage-0 registers, inverse FFT, direct store to planes 256..511.
// Round-15: k_fft_y processes TWO adjacent x-columns per thread as float4 (cpx2) —
// halves global/LDS instruction count + address math; LDS rows padded to 18 cpx.
// Inverse y (crop y<128, direct store) and inverse x + |.|^2 (crop x<128) finish.
// Complex algebra as ext_vector floats for packed v_pk_*_f32 (VOP3P).
// Twiddles stored as float4 (c, c, -s, s): cmul(a,w) = a*wl + swap(a)*wh.

typedef float __attribute__((ext_vector_type(2))) cpx;
typedef float __attribute__((ext_vector_type(4))) cpx2;   // two cpx (adjacent x columns)

__device__ float4 g_tw4[512];   // (c, c, -s, s), (c,s) = exp(-2*pi*i*k/512)

__device__ __forceinline__ cpx cswap(cpx a){ return __builtin_shufflevector(a, a, 1, 0); }
__device__ __forceinline__ cpx cmji(cpx a){ return cswap(a)*(cpx){1.0f, -1.0f}; }   // -i*a
__device__ __forceinline__ cpx cmpi(cpx a){ return cswap(a)*(cpx){-1.0f, 1.0f}; }   // +i*a

__device__ __forceinline__ cpx2 cswap2(cpx2 a){ return __builtin_shufflevector(a, a, 1, 0, 3, 2); }
__device__ __forceinline__ cpx2 cmji2(cpx2 a){ return cswap2(a)*(cpx2){1.0f, -1.0f, 1.0f, -1.0f}; }
__device__ __forceinline__ cpx2 cmpi2(cpx2 a){ return cswap2(a)*(cpx2){-1.0f, 1.0f, -1.0f, 1.0f}; }

// base-4 digit reversal of an 8-bit index
__device__ __forceinline__ int rev4_8(int k){
    return ((k & 3) << 6) | ((k & 12) << 2) | ((k >> 2) & 12) | (k >> 6);
}

// ---------------- twiddle table (double-computed for accuracy) ----------------
__global__ void k_tw(){
    int j = threadIdx.x;                        // 512 threads
    double a = -2.0*3.14159265358979323846*(double)j/512.0;
    float c = (float)cos(a), s = (float)sin(a);
    g_tw4[j] = make_float4(c, c, -s, s);
}

template<bool INV>
__device__ __forceinline__ cpx twmul(cpx a, int k){
    float4 t = g_tw4[k & 511];
    cpx wl = {t.x, t.y};
    cpx wh = {t.z, t.w};
    cpx r = a*wl;
    return INV ? (r - cswap(a)*wh) : (r + cswap(a)*wh);
}

template<bool INV>
__device__ __forceinline__ cpx2 twmul2(cpx2 a, int k){
    float4 t = g_tw4[k & 511];
    cpx2 wl = {t.x, t.y, t.x, t.y};
    cpx2 wh = {t.z, t.w, t.z, t.w};
    cpx2 r = a*wl;
    return INV ? (r - cswap2(a)*wh) : (r + cswap2(a)*wh);
}

// ---------------- radix-4 butterflies (cpx and cpx2 variants) ----------------
template<bool INV>
__device__ __forceinline__ void dft4(cpx* x){
    cpx e0 = x[0] + x[2], e1 = x[0] - x[2];
    cpx o0 = x[1] + x[3], o1 = x[1] - x[3];
    x[0] = e0 + o0;
    x[2] = e0 - o0;
    cpx j1 = INV ? cmpi(o1) : cmji(o1);
    x[1] = e1 + j1;
    x[3] = e1 - j1;
}
template<bool INV>
__device__ __forceinline__ void dft4_h2(cpx* x){
    cpx a0 = x[0], a1 = x[1];
    x[0] = a0 + a1;
    x[2] = a0 - a1;
    cpx j1 = INV ? cmpi(a1) : cmji(a1);
    x[1] = a0 + j1;
    x[3] = a0 - j1;
}
template<bool INV>
__device__ __forceinline__ void dft4_lo2(cpx* x){
    cpx e0 = x[0] + x[2], e1 = x[0] - x[2];
    cpx o0 = x[1] + x[3], o1 = x[1] - x[3];
    x[0] = e0 + o0;
    x[1] = e1 + (INV ? cmpi(o1) : cmji(o1));
}

template<bool INV>
__device__ __forceinline__ void dft4_2(cpx2* x){
    cpx2 e0 = x[0] + x[2], e1 = x[0] - x[2];
    cpx2 o0 = x[1] + x[3], o1 = x[1] - x[3];
    x[0] = e0 + o0;
    x[2] = e0 - o0;
    cpx2 j1 = INV ? cmpi2(o1) : cmji2(o1);
    x[1] = e1 + j1;
    x[3] = e1 - j1;
}
template<bool INV>
__device__ __forceinline__ void dft4_h2_2(cpx2* x){
    cpx2 a0 = x[0], a1 = x[1];
    x[0] = a0 + a1;
    x[2] = a0 - a1;
    cpx2 j1 = INV ? cmpi2(a1) : cmji2(a1);
    x[1] = a0 + j1;
    x[3] = a0 - j1;
}
template<bool INV>
__device__ __forceinline__ void dft4_lo2_2(cpx2* x){
    cpx2 e0 = x[0] + x[2], e1 = x[0] - x[2];
    cpx2 o0 = x[1] + x[3], o1 = x[1] - x[3];
    x[0] = e0 + o0;
    x[1] = e1 + (INV ? cmpi2(o1) : cmji2(o1));
}

// ---------------- radix-8 butterflies (cpx, for the z kernels) ----------------
template<bool INV>
__device__ __forceinline__ void dft8(cpx* x){
    const float s = 0.70710678118654752440f;
    cpx e0 = x[0] + x[4], e2 = x[0] - x[4];
    cpx e1 = x[2] + x[6], e3 = x[2] - x[6];
    cpx E0 = e0 + e1, E2 = e0 - e1;
    cpx j3 = INV ? cmpi(e3) : cmji(e3);
    cpx E1 = e2 + j3, E3 = e2 - j3;
    cpx o0 = x[1] + x[5], o2 = x[1] - x[5];
    cpx o1 = x[3] + x[7], o3 = x[3] - x[7];
    cpx O0 = o0 + o1, O2 = o0 - o1;
    cpx k3 = INV ? cmpi(o3) : cmji(o3);
    cpx O1 = o2 + k3, O3 = o2 - k3;
    cpx W1, W2, W3;
    if (!INV){
        W1 = s*(O1 + cmji(O1));
        W2 = cmji(O2);
        W3 = s*(cmji(O3) - O3);
    } else {
        W1 = s*(O1 + cmpi(O1));
        W2 = cmpi(O2);
        W3 = s*(cmpi(O3) - O3);
    }
    x[0] = E0 + O0; x[4] = E0 - O0;
    x[1] = E1 + W1; x[5] = E1 - W1;
    x[2] = E2 + W2; x[6] = E2 - W2;
    x[3] = E3 + W3; x[7] = E3 - W3;
}
template<bool INV>
__device__ __forceinline__ void dft8_h4(cpx* x){
    const float s = 0.70710678118654752440f;
    cpx a0 = x[0], a1 = x[1], a2 = x[2], a3 = x[3];
    cpx E0 = a0 + a2, E2 = a0 - a2;
    cpx j3 = INV ? cmpi(a2) : cmji(a2);
    cpx E1 = a0 + j3, E3 = a0 - j3;
    cpx O0 = a1 + a3, O2 = a1 - a3;
    cpx k3 = INV ? cmpi(a3) : cmji(a3);
    cpx O1 = a1 + k3, O3 = a1 - k3;
    cpx W1, W2, W3;
    if (!INV){
        W1 = s*(O1 + cmji(O1));
        W2 = cmji(O2);
        W3 = s*(cmji(O3) - O3);
    } else {
        W1 = s*(O1 + cmpi(O1));
        W2 = cmpi(O2);
        W3 = s*(cmpi(O3) - O3);
    }
    x[0] = E0 + O0; x[4] = E0 - O0;
    x[1] = E1 + W1; x[5] = E1 - W1;
    x[2] = E2 + W2; x[6] = E2 - W2;
    x[3] = E3 + W3; x[7] = E3 - W3;
}
template<bool INV>
__device__ __forceinline__ void dft8_lo4(cpx* x){
    const float s = 0.70710678118654752440f;
    cpx e0 = x[0] + x[4], e2 = x[0] - x[4];
    cpx e1 = x[2] + x[6], e3 = x[2] - x[6];
    cpx E0 = e0 + e1, E2 = e0 - e1;
    cpx j3 = INV ? cmpi(e3) : cmji(e3);
    cpx E1 = e2 + j3, E3 = e2 - j3;
    cpx o0 = x[1] + x[5], o2 = x[1] - x[5];
    cpx o1 = x[3] + x[7], o3 = x[3] - x[7];
    cpx O0 = o0 + o1, O2 = o0 - o1;
    cpx k3 = INV ? cmpi(o3) : cmji(o3);
    cpx O1 = o2 + k3, O3 = o2 - k3;
    cpx W1, W2, W3;
    if (!INV){
        W1 = s*(O1 + cmji(O1));
        W2 = cmji(O2);
        W3 = s*(cmji(O3) - O3);
    } else {
        W1 = s*(O1 + cmpi(O1));
        W2 = cmpi(O2);
        W3 = s*(cmpi(O3) - O3);
    }
    x[0] = E0 + O0;
    x[1] = E1 + W1;
    x[2] = E2 + W2;
    x[3] = E3 + W3;
}

// ---------------- 256-pt radix-4 FFT stages 1..3 on a contiguous LDS line ----------------
template<bool INV, bool CROP>
__device__ __forceinline__ void fft256_r4_tail(cpx* sl, int b){
    cpx x[4];
    {   // stage 1: stride 16, tw W_512^{8*j*r}
        int j = b & 15, g = (b >> 4) << 6;
        #pragma unroll
        for (int t = 0; t < 4; ++t) x[t] = sl[g + j + (t << 4)];
        dft4<INV>(x);
        #pragma unroll
        for (int r = 1; r < 4; ++r) x[r] = twmul<INV>(x[r], 8*j*r);
        #pragma unroll
        for (int r = 0; r < 4; ++r) sl[g + j + (r << 4)] = x[r];
    }
    __syncthreads();
    {   // stage 2: stride 4, tw W_512^{32*j*r}
        int j = b & 3, g = (b >> 2) << 4;
        #pragma unroll
        for (int t = 0; t < 4; ++t) x[t] = sl[g + j + (t << 2)];
        dft4<INV>(x);
        #pragma unroll
        for (int r = 1; r < 4; ++r) x[r] = twmul<INV>(x[r], 32*j*r);
        #pragma unroll
        for (int r = 0; r < 4; ++r) sl[g + j + (r << 2)] = x[r];
    }
    __syncthreads();
    {   // stage 3: stride 1, no twiddle
        int g = b << 2;
        #pragma unroll
        for (int t = 0; t < 4; ++t) x[t] = sl[g + t];
        if (CROP){
            dft4_lo2<INV>(x);
            sl[g] = x[0]; sl[g + 1] = x[1];
        } else {
            dft4<INV>(x);
            #pragma unroll
            for (int r = 0; r < 4; ++r) sl[g + r] = x[r];
        }
    }
    __syncthreads();
}

// ---------------- forward x-FFT fused with fill; store x-fftshifted AND x-half-blurred ----------------
__global__ __launch_bounds__(256) void k_fft_x_fill(const float* __restrict__ feat, cpx* __restrict__ V){
    __shared__ cpx s[4*256];                     // 8 KiB
    int tid = threadIdx.x;
    int line0 = blockIdx.x << 2;                 // line = z*128 + y, z<256, y<128
    int l = tid >> 6, b = tid & 63;
    int line = line0 + l;
    cpx* sl = s + l*256;
    {   // stage 0 from global: inputs positions b, b+64 (support x<128)
        int z = line >> 7;
        float g = (float)z*(1.0f/255.0f);
        const float* fl = feat + ((size_t)line << 7);
        float a  = fl[b]*g*g;       a  = a  > 0.0f ? sqrtf(a)  : 0.0f;
        float bb = fl[b + 64]*g*g;  bb = bb > 0.0f ? sqrtf(bb) : 0.0f;
        cpx x[4];
        x[0] = (cpx){a, 0.0f};
        x[1] = (cpx){bb, 0.0f};
        dft4_h2<false>(x);
        #pragma unroll
        for (int r = 1; r < 4; ++r) x[r] = twmul<false>(x[r], 2*b*r);
        #pragma unroll
        for (int r = 0; r < 4; ++r) sl[b + (r << 6)] = x[r];
    }
    __syncthreads();
    fft256_r4_tail<false, false>(sl, b);
    // blurred shifted store: F_s[e] sits at LDS pos rev4_8(e)^2 (rev4_8(128)=2)
    for (int i = tid; i < 4*128; i += 256){
        int ll = i >> 7, f4 = i & 127;
        int lin = line0 + ll;
        int base = ((lin >> 7) << 16) + ((lin & 127) << 8);
        const cpx* sll = s + ll*256;
        int e0 = 2*f4;
        cpx Fm = e0 ? sll[rev4_8(e0 - 1) ^ 2] : (cpx){0.0f, 0.0f};
        cpx F0 = sll[rev4_8(e0) ^ 2];
        cpx F1 = sll[rev4_8(e0 + 1) ^ 2];
        cpx o0 = 0.5f*(Fm + F0);
        cpx o1 = 0.5f*(F0 + F1);
        float4 o = make_float4(o0.x, o0.y, o1.x, o1.y);
        ((float4*)(V + base))[f4] = o;
    }
}

// ---------------- final inverse x-FFT fused with |.|^2, crop x<128; 4 lines/block ----------------
__global__ __launch_bounds__(256) void k_fft_x_inv_mag(const cpx* __restrict__ W,
                                                       float* __restrict__ out){
    __shared__ cpx s[4*256];                     // 8 KiB
    int tid = threadIdx.x;
    int line0 = blockIdx.x << 2;
    int l = tid >> 6, b = tid & 63;
    int line = line0 + l;
    int base = ((line >> 7) << 16) + ((line & 127) << 8);
    cpx* sl = s + l*256;
    {   // stage 0 from global: rows b+64t
        cpx x[4];
        #pragma unroll
        for (int t = 0; t < 4; ++t) x[t] = W[base + b + (t << 6)];
        dft4<true>(x);
        #pragma unroll
        for (int r = 1; r < 4; ++r) x[r] = twmul<true>(x[r], 2*b*r);
        #pragma unroll
        for (int r = 0; r < 4; ++r) sl[b + (r << 6)] = x[r];
    }
    __syncthreads();
    fft256_r4_tail<true, true>(sl, b);
    {
        int z = line >> 7, y = line & 127;
        cpx v0 = sl[rev4_8(2*b)];
        cpx v1 = sl[rev4_8(2*b + 1)];
        const float SC2 = (1.0f/33554432.0f)*(1.0f/33554432.0f);   // (1/(512*256*256))^2
        float2 o = make_float2((v0.x*v0.x + v0.y*v0.y)*SC2,
                               (v1.x*v1.x + v1.y*v1.y)*SC2);
        ((float2*)(out + (((size_t)(z*128 + y)) << 7)))[b] = o;
    }
}

// ---------------- FFT along y: 2 columns/thread (cpx2), 512 threads, LDS rows padded ----------------
// Stage 0 from global (float4 segments). Forward (HALF_IN): dft4_h2_2; store y-fftshifted
// AND y-half-blurred. Inverse (HALF_OUT): stage-3 dft4_lo2_2 + direct reg->global store.
#define YPAD 18   // LDS row stride in cpx (16 data + 2 pad -> 144B, rotates banks)
template<bool INV, bool HALF_IN, bool HALF_OUT>
__global__ __launch_bounds__(512, 8) void k_fft_y(cpx* __restrict__ V){
    __shared__ cpx s[256*YPAD];                 // 36 KiB
    int tid = threadIdx.x;
    int z  = blockIdx.x >> 4;
    int x0 = (blockIdx.x & 15) << 4;
    int base = (z << 16) + x0;
    int c2 = tid & 7, idx = tid >> 3;           // c2: column pair, idx in [0,64)
    int co = c2 << 1;                           // column offset (0,2,..,14)
    cpx2 x[4];
    {   // stage 0: rows idx+64t from global, tw W_512^{2*j*r}
        int j = idx;
        if (HALF_IN){
            x[0] = *(const cpx2*)(V + base + (j << 8) + co);
            x[1] = *(const cpx2*)(V + base + ((j + 64) << 8) + co);
            dft4_h2_2<INV>(x);
        } else {
            #pragma unroll
            for (int t = 0; t < 4; ++t)
                x[t] = *(const cpx2*)(V + base + ((j + (t << 6)) << 8) + co);
            dft4_2<INV>(x);
        }
        #pragma unroll
        for (int r = 1; r < 4; ++r) x[r] = twmul2<INV>(x[r], 2*j*r);
        #pragma unroll
        for (int r = 0; r < 4; ++r) *(cpx2*)(s + (j + (r << 6))*YPAD + co) = x[r];
    }
    __syncthreads();
    {   // stage 1: stride 16, tw W_512^{8*j*r}
        int j = idx & 15, g = (idx >> 4) << 6;
        #pragma unroll
        for (int t = 0; t < 4; ++t) x[t] = *(const cpx2*)(s + (g + j + (t << 4))*YPAD + co);
        dft4_2<INV>(x);
        #pragma unroll
        for (int r = 1; r < 4; ++r) x[r] = twmul2<INV>(x[r], 8*j*r);
        #pragma unroll
        for (int r = 0; r < 4; ++r) *(cpx2*)(s + (g + j + (r << 4))*YPAD + co) = x[r];
    }
    __syncthreads();
    {   // stage 2: stride 4, tw W_512^{32*j*r}
        int j = idx & 3, g = (idx >> 2) << 4;
        #pragma unroll
        for (int t = 0; t < 4; ++t) x[t] = *(const cpx2*)(s + (g + j + (t << 2))*YPAD + co);
        dft4_2<INV>(x);
        #pragma unroll
        for (int r = 1; r < 4; ++r) x[r] = twmul2<INV>(x[r], 32*j*r);
        #pragma unroll
        for (int r = 0; r < 4; ++r) *(cpx2*)(s + (g + j + (r << 2))*YPAD + co) = x[r];
    }
    __syncthreads();
    if (HALF_OUT){
        // stage 3 + direct store: positions g,g+1 = bins rev4(g), rev4(g)+64 (both <128)
        int g = idx << 2;
        #pragma unroll
        for (int t = 0; t < 4; ++t) x[t] = *(const cpx2*)(s + (g + t)*YPAD + co);
        dft4_lo2_2<INV>(x);
        int e0 = rev4_8(g);                      // < 64
        *(cpx2*)(V + base + (e0 << 8) + co) = x[0];
        *(cpx2*)(V + base + ((e0 + 64) << 8) + co) = x[1];
        return;
    }
    {   // stage 3 full
        int g = idx << 2;
        #pragma unroll
        for (int t = 0; t < 4; ++t) x[t] = *(const cpx2*)(s + (g + t)*YPAD + co);
        dft4_2<INV>(x);
        #pragma unroll
        for (int r = 0; r < 4; ++r) *(cpx2*)(s + (g + r)*YPAD + co) = x[r];
    }
    __syncthreads();
    // blurred shifted store: pos e = 0.5*(F_s[e-1] + F_s[e]); F_s[q] at row rev4(q)^2
    for (int i = tid; i < 256*8; i += 512){
        int f4c = i & 7, e = i >> 3;
        int p0 = rev4_8(e) ^ 2;
        cpx2 S0 = ((const cpx2*)(s + p0*YPAD))[f4c];
        cpx2 S1 = (cpx2){0.0f, 0.0f, 0.0f, 0.0f};
        if (e){
            int p1 = rev4_8(e - 1) ^ 2;
            S1 = ((const cpx2*)(s + p1*YPAD))[f4c];
        }
        cpx2 o = 0.5f*(S0 + S1);
        ((cpx2*)(V + base + (e << 8)))[f4c] = o;
    }
}

// ---------------- FUSED z-stage: fwd z-FFT (partner source column) + Stolt gather +
// inverse z-FFT, one 64 KiB buffer, 6 barriers. Reads planes 0..255 only; writes dest
// to planes 256..511 (disjoint -> race-free across blocks). ----------------
__global__ __launch_bounds__(1024, 8) void k_fftz_fused(cpx* __restrict__ V){
    __shared__ cpx s[512*16];                   // 64 KiB
    int tid = threadIdx.x;
    int yD  = blockIdx.x >> 4;
    int x0D = (blockIdx.x & 15) << 4;
    int baseD = (yD << 8) + x0D;
    int yS  = (yD + 128) & 255;
    int x0S = (x0D + 128) & 255;                // 16-aligned; x0S+c stays in tile
    int baseS = (yS << 8) + x0S;
    int c = tid & 15, idx = tid >> 4;
    cpx x[8];
    int j = idx;
    {   // fwd stage 0: source planes j+64t (t<4 nonzero) straight from global
        #pragma unroll
        for (int t = 0; t < 4; ++t)
            x[t] = V[baseS + (((size_t)(j + (t << 6))) << 16) + c];
        dft8_h4<false>(x);
        #pragma unroll
        for (int r = 1; r < 8; ++r) x[r] = twmul<false>(x[r], j*r);
        #pragma unroll
        for (int r = 0; r < 8; ++r) s[(j + (r << 6))*16 + c] = x[r];
    }
    __syncthreads();
    {   // fwd stage 1
        int jj = idx & 7, g = (idx >> 3) << 6;
        #pragma unroll
        for (int t = 0; t < 8; ++t) x[t] = s[(g + jj + (t << 3))*16 + c];
        dft8<false>(x);
        #pragma unroll
        for (int r = 1; r < 8; ++r) x[r] = twmul<false>(x[r], 8*jj*r);
        #pragma unroll
        for (int r = 0; r < 8; ++r) s[(g + jj + (r << 3))*16 + c] = x[r];
    }
    __syncthreads();
    {   // fwd stage 2 lo4: write bins 0..255 at NATURAL rows e = rev8(position)
        int g = idx << 3;
        #pragma unroll
        for (int t = 0; t < 8; ++t) x[t] = s[(g + t)*16 + c];
        dft8_lo4<false>(x);
        #pragma unroll
        for (int r = 0; r < 4; ++r){
            int e = (r << 6) | ((idx & 7) << 3) | (idx >> 3);   // rev8_9(g+r), < 256
            s[e*16 + c] = x[r];
        }
    }
    __syncthreads();
    // Stolt gather (dest coords = source position) -> inverse stage-0 registers
    {
        int xs = x0S + c;
        float gx = (float)(xs - 128)*(1.0f/128.0f);
        float gy = (float)(yS - 128)*(1.0f/128.0f);
        float rxy = 0.1024f*(gx*gx + gy*gy);
        #pragma unroll
        for (int t = 0; t < 4; ++t){
            int zd = j + (t << 6);
            cpx r = (cpx){0.0f, 0.0f};
            if (zd){
                float gz = (float)zd*(1.0f/256.0f);
                float gzn = sqrtf(rxy + gz*gz);
                float iz = ((gzn + 1.0f)*512.0f - 1.0f)*0.5f;
                float fiz = floorf(iz);
                int iz0 = (int)fiz;              // in [256, ~536)
                float fz = iz - fiz;
                float sc = gz/(gzn + 1e-8f);
                int b0 = (iz0 < 511 ? iz0 : 511) - 256;
                int b1 = ((iz0 + 1) < 511 ? (iz0 + 1) : 511) - 256;
                float w0 = (iz0     <= 511) ? (1.0f - fz)*sc : 0.0f;
                float w1 = (iz0 + 1 <= 511) ? fz*sc : 0.0f;
                cpx a = s[(b0 << 4) + c];        // natural-row fwd bins
                cpx b = s[(b1 << 4) + c];
                r = a*w0 + b*w1;
            }
            x[t] = r;
        }
        dft8_h4<true>(x);
        #pragma unroll
        for (int r = 1; r < 8; ++r) x[r] = twmul<true>(x[r], j*r);
    }
    __syncthreads();                             // all gather reads done before overwrite
    {
        #pragma unroll
        for (int r = 0; r < 8; ++r) s[(j + (r << 6))*16 + c] = x[r];
    }
    __syncthreads();
    {   // inv stage 1
        int jj = idx & 7, g = (idx >> 3) << 6;
        #pragma unroll
        for (int t = 0; t < 8; ++t) x[t] = s[(g + jj + (t << 3))*16 + c];
        dft8<true>(x);
        #pragma unroll
        for (int r = 1; r < 8; ++r) x[r] = twmul<true>(x[r], 8*jj*r);
        #pragma unroll
        for (int r = 0; r < 8; ++r) s[(g + jj + (r << 3))*16 + c] = x[r];
    }
    __syncthreads();
    {   // inv stage 2 lo4 + DIRECT store of z<256 to dest planes 256..511
        int g = idx << 3;
        #pragma unroll
        for (int t = 0; t < 8; ++t) x[t] = s[(g + t)*16 + c];
        dft8_lo4<true>(x);
        #pragma unroll
        for (int r = 0; r < 4; ++r){
            int e = (r << 6) | ((idx & 7) << 3) | (idx >> 3);   // rev8_9(g+r), < 256
            V[baseD + (((size_t)(e + 256)) << 16) + c] = x[r];
        }
    }
}

extern "C" void kernel_launch(void* const* d_in, const int* in_sizes, int n_in,
                              void* d_out, int out_size, void* d_ws, size_t ws_size,
                              hipStream_t stream){
    const float* feat = (const float*)d_in[0];   // [1,1,256,128,128] f32; tbes=0, tens=256
    float* out = (float*)d_out;                  // [1,1,256,128,128] f32

    const size_t WS_NEED = (size_t)512*256*256*8;   // 268,435,456 B exactly
    if (ws_size < WS_NEED){
        hipMemsetAsync(d_out, 0, (size_t)out_size*sizeof(float), stream);
        return;
    }
    cpx* V  = (cpx*)d_ws;
    cpx* Vu = V + (size_t)256*65536;             // planes 256..511 (post-z result)

    k_tw<<<1, 512, 0, stream>>>();
    // forward x (+fill,+x-blur) and y (+y-blur), stored fftshifted, planes 0..255
    k_fft_x_fill<<<8192, 256, 0, stream>>>(feat, V);                // 4 lines/block
    k_fft_y<false, true, false><<<4096, 512, 0, stream>>>(V);       // z<256; y<128 in, blurred y out
    // fused z-stage: fwd FFT of partner column + gather + inv FFT -> planes 256..511
    k_fftz_fused<<<4096, 1024, 0, stream>>>(V);
    // inverse y + inverse x (+|.|^2) on planes 256..511 via offset base pointer
    k_fft_y<true, false, true><<<4096, 512, 0, stream>>>(Vu);       // full y in, y<128 out (direct store)
    k_fft_x_inv_mag<<<8192, 256, 0, stream>>>(Vu, out);             // 4 lines/block, |.|^2, x<128
}